// Round 2
// baseline (669.099 us; speedup 1.0000x reference)
//
#include <hip/hip_runtime.h>
#include <math.h>

#define B 4
#define T 8192
#define D 512
#define NN 256
#define L 768
#define TE 2048
#define H 8
#define DH 64
#define RPB 16
#define QS 516   // padded LDS row stride (516 % 32 = 4 -> spreads per-row banks)

__device__ __forceinline__ float sigmoidf_(float x){ return 1.0f/(1.0f+__expf(-x)); }

// ---------------- K1: scale/shift = silu(emb) @ emb_W + emb_b  -> ss[B][1024]
__global__ void k_ss(const float* __restrict__ emb, const float* __restrict__ emb_W,
                     const float* __restrict__ emb_b, float* __restrict__ ss){
    __shared__ float semb[TE];
    __shared__ float red[16][17];
    int t = threadIdx.x, c = blockIdx.x, b = blockIdx.y;
    for (int i = t; i < TE; i += 256){ float e = emb[b*TE + i]; semb[i] = e * sigmoidf_(e); }
    __syncthreads();
    int o = t & 15, p = t >> 4;
    int j = c*16 + o;
    float acc = 0.f;
    #pragma unroll 4
    for (int i = 0; i < TE/16; ++i){ int e = p*(TE/16) + i; acc += semb[e]*emb_W[e*1024 + j]; }
    red[p][o] = acc;
    __syncthreads();
    if (p == 0){
        float s = 0.f;
        #pragma unroll
        for (int pp = 0; pp < 16; ++pp) s += red[pp][o];
        ss[b*1024 + j] = s + emb_b[j];
    }
}

// ---------------- K2: xfn = LN(xf); k = xfn@Wk+bk; v = xfn@Wv+bv
__global__ void k_kv(const float* __restrict__ xf, const float* __restrict__ Wk,
                     const float* __restrict__ bk, const float* __restrict__ Wv,
                     const float* __restrict__ bv, const float* __restrict__ tg,
                     const float* __restrict__ tb, float* __restrict__ kbuf,
                     float* __restrict__ vbuf){
    __shared__ float xfn[4][L];
    int t = threadIdx.x;
    int wave = t >> 6, lane = t & 63;
    int g0 = blockIdx.x * 4;
    {   // LN: wave w handles row w (768 elems, 12/lane)
        int r = wave; int g = g0 + r;
        float vals[12];
        float s = 0.f, sq = 0.f;
        #pragma unroll
        for (int i = 0; i < 12; ++i){ float v = xf[(size_t)g*L + lane*12 + i]; vals[i] = v; s += v; sq += v*v; }
        #pragma unroll
        for (int o = 32; o; o >>= 1){ s += __shfl_xor(s, o); sq += __shfl_xor(sq, o); }
        float m = s / L; float var = sq / L - m*m;
        float rstd = rsqrtf(var + 1e-5f);
        #pragma unroll
        for (int i = 0; i < 12; ++i){
            int l = lane*12 + i;
            xfn[r][l] = (vals[i]-m)*rstd*tg[l] + tb[l];
        }
    }
    __syncthreads();
    float ak[4][2] = {{0.f}}, av[4][2] = {{0.f}};
    for (int l = 0; l < L; l += 4){
        float4 xv[4];
        #pragma unroll
        for (int r = 0; r < 4; ++r) xv[r] = *(const float4*)&xfn[r][l];
        #pragma unroll
        for (int u = 0; u < 4; ++u){
            int lu = l + u;
            float wk0 = Wk[lu*D + t], wk1 = Wk[lu*D + t + 256];
            float wv0 = Wv[lu*D + t], wv1 = Wv[lu*D + t + 256];
            #pragma unroll
            for (int r = 0; r < 4; ++r){
                float xr = ((const float*)&xv[r])[u];
                ak[r][0] += xr*wk0; ak[r][1] += xr*wk1;
                av[r][0] += xr*wv0; av[r][1] += xr*wv1;
            }
        }
    }
    float bk0 = bk[t], bk1 = bk[t+256], bv0 = bv[t], bv1 = bv[t+256];
    #pragma unroll
    for (int r = 0; r < 4; ++r){
        size_t g = (size_t)(g0 + r);
        kbuf[g*D + t] = ak[r][0] + bk0; kbuf[g*D + t + 256] = ak[r][1] + bk1;
        vbuf[g*D + t] = av[r][0] + bv0; vbuf[g*D + t + 256] = av[r][1] + bv1;
    }
}

// ---------------- K3: k-softmax over N and att[b][h] = k_sm^T @ v
__global__ void k_att(const float* __restrict__ kbuf, const float* __restrict__ vbuf,
                      float* __restrict__ att){
    __shared__ float kh[NN*DH];   // 64 KB
    __shared__ float vh[NN*DH];   // 64 KB
    __shared__ float rm[DH], rs[DH];
    int t = threadIdx.x, h = blockIdx.x, b = blockIdx.y;
    for (int k = 0; k < NN*DH/256; ++k){
        int m = k*256 + t;
        int n = m >> 6, dl = m & 63;
        size_t src = (size_t)(b*NN + n)*D + h*DH + dl;
        kh[m] = kbuf[src]; vh[m] = vbuf[src];
    }
    __syncthreads();
    if (t < DH){
        float mx = -1e30f;
        for (int n = 0; n < NN; ++n) mx = fmaxf(mx, kh[n*DH + t]);
        float s = 0.f;
        for (int n = 0; n < NN; ++n) s += __expf(kh[n*DH + t] - mx);
        rm[t] = mx; rs[t] = 1.0f/s;
    }
    __syncthreads();
    for (int k = 0; k < NN*DH/256; ++k){
        int m = k*256 + t; int dd = m & 63;
        kh[m] = __expf(kh[m] - rm[dd]) * rs[dd];
    }
    __syncthreads();
    int dd = t >> 2, dl0 = (t & 3)*16;
    float acc[16] = {0.f};
    for (int n = 0; n < NN; ++n){
        float kv = kh[n*DH + dd];
        #pragma unroll
        for (int i = 0; i < 16; ++i) acc[i] += kv * vh[n*DH + dl0 + i];
    }
    size_t base = ((size_t)(b*H + h)*DH + dd)*DH + dl0;
    #pragma unroll
    for (int i = 0; i < 16; ++i) att[base + i] = acc[i];
}

// ---------------- K4: main fused kernel over 16-row blocks of (B*T)
__global__ __launch_bounds__(256, 2) void k_main(
    const float* __restrict__ x, const float* __restrict__ Wq, const float* __restrict__ bq,
    const float* __restrict__ lg, const float* __restrict__ lb,
    const float* __restrict__ att, const float* __restrict__ ss,
    const float* __restrict__ sg, const float* __restrict__ sb,
    const float* __restrict__ oW, const float* __restrict__ ob,
    float* __restrict__ out){
    __shared__ float bufA[RPB*QS];
    __shared__ float bufB[RPB*QS];
    int t = threadIdx.x, wave = t >> 6, lane = t & 63;
    long g0 = (long)blockIdx.x * RPB;
    int b = (int)(g0 / T);

    // a) LN(x) -> bufA  (wave w reduces rows 4w..4w+3)
    for (int rr = 0; rr < 4; ++rr){
        int r = wave*4 + rr; long g = g0 + r;
        float4 v0 = *(const float4*)&x[g*D + lane*8];
        float4 v1 = *(const float4*)&x[g*D + lane*8 + 4];
        float s  = v0.x+v0.y+v0.z+v0.w + v1.x+v1.y+v1.z+v1.w;
        float sq = v0.x*v0.x+v0.y*v0.y+v0.z*v0.z+v0.w*v0.w
                 + v1.x*v1.x+v1.y*v1.y+v1.z*v1.z+v1.w*v1.w;
        #pragma unroll
        for (int o = 32; o; o >>= 1){ s += __shfl_xor(s,o); sq += __shfl_xor(sq,o); }
        float m = s/D, var = sq/D - m*m, rstd = rsqrtf(var+1e-5f);
        float vv[8] = {v0.x,v0.y,v0.z,v0.w,v1.x,v1.y,v1.z,v1.w};
        #pragma unroll
        for (int i = 0; i < 8; ++i){
            int l = lane*8 + i;
            bufA[r*QS + l] = (vv[i]-m)*rstd*lg[l] + lb[l];
        }
    }
    __syncthreads();

    // b) GEMM1: q = LN(x) @ Wq + bq  -> bufB
    {
        float acc[RPB][2] = {{0.f}};
        for (int l = 0; l < D; l += 4){
            float4 a[RPB];
            #pragma unroll
            for (int r = 0; r < RPB; ++r) a[r] = *(const float4*)&bufA[r*QS + l];
            #pragma unroll
            for (int u = 0; u < 4; ++u){
                float w0 = Wq[(l+u)*D + t], w1 = Wq[(l+u)*D + t + 256];
                #pragma unroll
                for (int r = 0; r < RPB; ++r){
                    float xr = ((const float*)&a[r])[u];
                    acc[r][0] += xr*w0; acc[r][1] += xr*w1;
                }
            }
        }
        float b0 = bq[t], b1 = bq[t+256];
        #pragma unroll
        for (int r = 0; r < RPB; ++r){
            bufB[r*QS + t]       = acc[r][0] + b0;
            bufB[r*QS + t + 256] = acc[r][1] + b1;
        }
    }
    __syncthreads();

    // c) per-(row,head) softmax over 64, in place in bufB
    if (t < 128){
        int r = t >> 3, h = t & 7;
        float* p = &bufB[r*QS + h*DH];
        float mx = -1e30f;
        for (int i = 0; i < DH; ++i) mx = fmaxf(mx, p[i]);
        float s = 0.f;
        for (int i = 0; i < DH; ++i){ float e = __expf(p[i]-mx); p[i] = e; s += e; }
        float inv = 1.0f/s;
        for (int i = 0; i < DH; ++i) p[i] *= inv;
    }
    __syncthreads();

    // d) y = q @ att[b]  -> bufA (overwrites LN(x), no longer needed)
    {
        int h = t >> 5, dl0 = (2*t) & 63;
        const float* ah = &att[(size_t)(b*H + h)*DH*DH];
        float ya[RPB][2] = {{0.f}};
        for (int dd = 0; dd < DH; dd += 4){
            float4 qv[RPB];
            #pragma unroll
            for (int r = 0; r < RPB; ++r) qv[r] = *(const float4*)&bufB[r*QS + h*DH + dd];
            #pragma unroll
            for (int u = 0; u < 4; ++u){
                float2 av = *(const float2*)&ah[(dd+u)*DH + dl0];
                #pragma unroll
                for (int r = 0; r < RPB; ++r){
                    float qq = ((const float*)&qv[r])[u];
                    ya[r][0] += qq*av.x; ya[r][1] += qq*av.y;
                }
            }
        }
        int j = h*DH + dl0;
        #pragma unroll
        for (int r = 0; r < RPB; ++r){
            *(float2*)&bufA[r*QS + j] = make_float2(ya[r][0], ya[r][1]);
        }
    }
    __syncthreads();

    // e) LN(y) * (1+scale) + shift, then silu, in place in bufA
    for (int rr = 0; rr < 4; ++rr){
        int r = wave*4 + rr;
        float vals[8];
        float s = 0.f, sq = 0.f;
        #pragma unroll
        for (int i = 0; i < 8; ++i){ float v = bufA[r*QS + lane*8 + i]; vals[i] = v; s += v; sq += v*v; }
        #pragma unroll
        for (int o = 32; o; o >>= 1){ s += __shfl_xor(s,o); sq += __shfl_xor(sq,o); }
        float m = s/D, var = sq/D - m*m, rstd = rsqrtf(var+1e-5f);
        #pragma unroll
        for (int i = 0; i < 8; ++i){
            int l = lane*8 + i;
            float yn = (vals[i]-m)*rstd*sg[l] + sb[l];
            float sc = ss[b*1024 + l], sh = ss[b*1024 + D + l];
            float hh = yn*(1.f+sc) + sh;
            bufA[r*QS + l] = hh * sigmoidf_(hh);
        }
    }
    __syncthreads();

    // f) GEMM2: out = silu(h) @ out_W + out_b + x
    {
        float acc[RPB][2] = {{0.f}};
        for (int l = 0; l < D; l += 4){
            float4 a[RPB];
            #pragma unroll
            for (int r = 0; r < RPB; ++r) a[r] = *(const float4*)&bufA[r*QS + l];
            #pragma unroll
            for (int u = 0; u < 4; ++u){
                float w0 = oW[(l+u)*D + t], w1 = oW[(l+u)*D + t + 256];
                #pragma unroll
                for (int r = 0; r < RPB; ++r){
                    float xr = ((const float*)&a[r])[u];
                    acc[r][0] += xr*w0; acc[r][1] += xr*w1;
                }
            }
        }
        float b0 = ob[t], b1 = ob[t+256];
        #pragma unroll
        for (int r = 0; r < RPB; ++r){
            long g = g0 + r;
            out[g*D + t]       = acc[r][0] + b0 + x[g*D + t];
            out[g*D + t + 256] = acc[r][1] + b1 + x[g*D + t + 256];
        }
    }
}

extern "C" void kernel_launch(void* const* d_in, const int* in_sizes, int n_in,
                              void* d_out, int out_size, void* d_ws, size_t ws_size,
                              hipStream_t stream){
    const float* x     = (const float*)d_in[0];
    const float* xf    = (const float*)d_in[1];
    const float* emb   = (const float*)d_in[2];
    const float* Wq    = (const float*)d_in[3];
    const float* bq    = (const float*)d_in[4];
    const float* Wk    = (const float*)d_in[5];
    const float* bk    = (const float*)d_in[6];
    const float* Wv    = (const float*)d_in[7];
    const float* bv    = (const float*)d_in[8];
    const float* ln_g  = (const float*)d_in[9];
    const float* ln_b  = (const float*)d_in[10];
    const float* tln_g = (const float*)d_in[11];
    const float* tln_b = (const float*)d_in[12];
    const float* emb_W = (const float*)d_in[13];
    const float* emb_b = (const float*)d_in[14];
    const float* sn_g  = (const float*)d_in[15];
    const float* sn_b  = (const float*)d_in[16];
    const float* out_W = (const float*)d_in[17];
    const float* out_b = (const float*)d_in[18];
    float* out = (float*)d_out;
    float* ws  = (float*)d_ws;

    float* ss   = ws;                    // B*1024           = 4096
    float* kbuf = ss + B*1024;           // B*NN*D           = 524288
    float* vbuf = kbuf + (size_t)B*NN*D; // B*NN*D           = 524288
    float* att  = vbuf + (size_t)B*NN*D; // B*H*DH*DH        = 131072

    k_ss <<<dim3(64, B),    dim3(256), 0, stream>>>(emb, emb_W, emb_b, ss);
    k_kv <<<dim3(B*NN/4),   dim3(256), 0, stream>>>(xf, Wk, bk, Wv, bv, tln_g, tln_b, kbuf, vbuf);
    k_att<<<dim3(H, B),     dim3(256), 0, stream>>>(kbuf, vbuf, att);
    k_main<<<dim3(B*T/RPB), dim3(256), 0, stream>>>(x, Wq, bq, ln_g, ln_b, att, ss,
                                                    sn_g, sn_b, out_W, out_b, out);
}

// Round 3
// 258.986 us; speedup vs baseline: 2.5835x; 2.5835x over previous
//
#include <hip/hip_runtime.h>
#include <math.h>

#define B 4
#define T 8192
#define D 512
#define NN 256
#define L 768
#define TE 2048
#define H 8
#define DH 64
#define MR 64          // rows per k_main block
#define AS 520         // Abuf row stride in bf16 (+8 pad -> 1040B, 2-way bank alias only)

typedef __bf16 bf16;
typedef bf16  bf16x8 __attribute__((ext_vector_type(8)));
typedef float f32x4  __attribute__((ext_vector_type(4)));

__device__ __forceinline__ float sigmoidf_(float x){ return 1.0f/(1.0f+__expf(-x)); }

// ---------------- prep: Wt[n][k] = bf16(W[k][n])  (512x512)
__global__ void k_wprep(const float* __restrict__ W, bf16* __restrict__ Wt){
    __shared__ float tile[64][65];
    int t = threadIdx.x;
    int k0 = blockIdx.x*64, n0 = blockIdx.y*64;
    int c = t & 63, r4 = t >> 6;
    #pragma unroll
    for (int p = 0; p < 16; ++p){ int r = p*4 + r4; tile[r][c] = W[(size_t)(k0+r)*D + n0 + c]; }
    __syncthreads();
    #pragma unroll
    for (int p = 0; p < 16; ++p){ int n = p*4 + r4; Wt[(size_t)(n0+n)*D + k0 + c] = (bf16)tile[c][n]; }
}

// ---------------- K1: scale/shift = silu(emb) @ emb_W + emb_b  -> ss[B][1024]
__global__ void k_ss(const float* __restrict__ emb, const float* __restrict__ emb_W,
                     const float* __restrict__ emb_b, float* __restrict__ ss){
    __shared__ float semb[TE];
    __shared__ float red[16][17];
    int t = threadIdx.x, c = blockIdx.x, b = blockIdx.y;
    for (int i = t; i < TE; i += 256){ float e = emb[b*TE + i]; semb[i] = e * sigmoidf_(e); }
    __syncthreads();
    int o = t & 15, p = t >> 4;
    int j = c*16 + o;
    float acc = 0.f;
    #pragma unroll 4
    for (int i = 0; i < TE/16; ++i){ int e = p*(TE/16) + i; acc += semb[e]*emb_W[e*1024 + j]; }
    red[p][o] = acc;
    __syncthreads();
    if (p == 0){
        float s = 0.f;
        #pragma unroll
        for (int pp = 0; pp < 16; ++pp) s += red[pp][o];
        ss[b*1024 + j] = s + emb_b[j];
    }
}

// ---------------- K2: xfn = LN(xf); k = xfn@Wk+bk; v = xfn@Wv+bv  (bf16 out)
__global__ void k_kv(const float* __restrict__ xf, const float* __restrict__ Wk,
                     const float* __restrict__ bk, const float* __restrict__ Wv,
                     const float* __restrict__ bv, const float* __restrict__ tg,
                     const float* __restrict__ tb, bf16* __restrict__ kbuf,
                     bf16* __restrict__ vbuf){
    __shared__ float xfn[4][L];
    int t = threadIdx.x;
    int wave = t >> 6, lane = t & 63;
    int g0 = blockIdx.x * 4;
    {
        int r = wave; int g = g0 + r;
        float vals[12];
        float s = 0.f, sq = 0.f;
        #pragma unroll
        for (int i = 0; i < 12; ++i){ float v = xf[(size_t)g*L + lane*12 + i]; vals[i] = v; s += v; sq += v*v; }
        #pragma unroll
        for (int o = 32; o; o >>= 1){ s += __shfl_xor(s, o); sq += __shfl_xor(sq, o); }
        float m = s / L; float var = sq / L - m*m;
        float rstd = rsqrtf(var + 1e-5f);
        #pragma unroll
        for (int i = 0; i < 12; ++i){
            int l = lane*12 + i;
            xfn[r][l] = (vals[i]-m)*rstd*tg[l] + tb[l];
        }
    }
    __syncthreads();
    float ak[4][2] = {{0.f}}, av[4][2] = {{0.f}};
    for (int l = 0; l < L; l += 4){
        float4 xv[4];
        #pragma unroll
        for (int r = 0; r < 4; ++r) xv[r] = *(const float4*)&xfn[r][l];
        #pragma unroll
        for (int u = 0; u < 4; ++u){
            int lu = l + u;
            float wk0 = Wk[lu*D + t], wk1 = Wk[lu*D + t + 256];
            float wv0 = Wv[lu*D + t], wv1 = Wv[lu*D + t + 256];
            #pragma unroll
            for (int r = 0; r < 4; ++r){
                float xr = ((const float*)&xv[r])[u];
                ak[r][0] += xr*wk0; ak[r][1] += xr*wk1;
                av[r][0] += xr*wv0; av[r][1] += xr*wv1;
            }
        }
    }
    float bk0 = bk[t], bk1 = bk[t+256], bv0 = bv[t], bv1 = bv[t+256];
    #pragma unroll
    for (int r = 0; r < 4; ++r){
        size_t g = (size_t)(g0 + r);
        kbuf[g*D + t]       = (bf16)(ak[r][0] + bk0);
        kbuf[g*D + t + 256] = (bf16)(ak[r][1] + bk1);
        vbuf[g*D + t]       = (bf16)(av[r][0] + bv0);
        vbuf[g*D + t + 256] = (bf16)(av[r][1] + bv1);
    }
}

// ---------------- K3: k-softmax over N; attT[b][h][l][d] = sum_n k_sm[n,d] v[n,l]  (bf16)
__global__ void k_att(const bf16* __restrict__ kbuf, const bf16* __restrict__ vbuf,
                      bf16* __restrict__ attT){
    __shared__ float kh[NN*DH];
    __shared__ float vh[NN*DH];
    __shared__ float rm[DH], rs[DH];
    int t = threadIdx.x, h = blockIdx.x, b = blockIdx.y;
    for (int k = 0; k < NN*DH/256; ++k){
        int m = k*256 + t;
        int n = m >> 6, dl = m & 63;
        size_t src = (size_t)(b*NN + n)*D + h*DH + dl;
        kh[m] = (float)kbuf[src]; vh[m] = (float)vbuf[src];
    }
    __syncthreads();
    if (t < DH){
        float mx = -1e30f;
        for (int n = 0; n < NN; ++n) mx = fmaxf(mx, kh[n*DH + t]);
        float s = 0.f;
        for (int n = 0; n < NN; ++n) s += __expf(kh[n*DH + t] - mx);
        rm[t] = mx; rs[t] = 1.0f/s;
    }
    __syncthreads();
    for (int k = 0; k < NN*DH/256; ++k){
        int m = k*256 + t; int dd = m & 63;
        kh[m] = __expf(kh[m] - rm[dd]) * rs[dd];
    }
    __syncthreads();
    int dl = t >> 2, dd0 = (t & 3)*16;
    float acc[16] = {0.f};
    for (int n = 0; n < NN; ++n){
        float vv = vh[n*DH + dl];
        #pragma unroll
        for (int i = 0; i < 16; ++i) acc[i] += kh[n*DH + dd0 + i] * vv;
    }
    size_t base = (((size_t)b*H + h)*DH + dl)*DH + dd0;
    bf16x8 o0, o1;
    #pragma unroll
    for (int i = 0; i < 8; ++i){ o0[i] = (bf16)acc[i]; o1[i] = (bf16)acc[8+i]; }
    *(bf16x8*)&attT[base]     = o0;
    *(bf16x8*)&attT[base + 8] = o1;
}

// ---------------- MFMA GEMM helper: acc[mt][nt] += A(64xD from LDS) * Wt(B, [n][k] bf16, from L2)
__device__ __forceinline__ void gemm512(const bf16* __restrict__ Wt, const bf16* Ab,
                                        int wb, int l15, int grp, f32x4 acc[4][8]){
    const bf16* wbase[8];
    #pragma unroll
    for (int nt = 0; nt < 8; ++nt)
        wbase[nt] = Wt + (size_t)(wb + nt*16 + l15)*D + grp*8;
    #pragma unroll
    for (int ks = 0; ks < 16; ++ks){
        bf16x8 aa[4];
        #pragma unroll
        for (int mt = 0; mt < 4; ++mt)
            aa[mt] = *(const bf16x8*)&Ab[(mt*16 + l15)*AS + ks*32 + grp*8];
        #pragma unroll
        for (int nt = 0; nt < 8; ++nt){
            bf16x8 bb = *(const bf16x8*)&wbase[nt][ks*32];
            #pragma unroll
            for (int mt = 0; mt < 4; ++mt)
                acc[mt][nt] = __builtin_amdgcn_mfma_f32_16x16x32_bf16(aa[mt], bb, acc[mt][nt], 0, 0, 0);
        }
    }
}

// ---------------- K4: main fused kernel, 64 rows/block, MFMA GEMMs
__global__ __launch_bounds__(256, 2) void k_main(
    const float* __restrict__ x, const bf16* __restrict__ WqT, const float* __restrict__ bq,
    const float* __restrict__ lg, const float* __restrict__ lb,
    const bf16* __restrict__ attT, const float* __restrict__ ssb,
    const float* __restrict__ sg, const float* __restrict__ sb,
    const bf16* __restrict__ oWT, const float* __restrict__ ob,
    float* __restrict__ out){
    __shared__ __align__(16) bf16 Abuf[MR*AS];   // 66.6 KB, reused LN(x)->q->silu(h)
    __shared__ float st_s[MR][4];
    __shared__ float st_q[MR][4];
    const int t = threadIdx.x, w = t >> 6, lane = t & 63;
    const int l15 = lane & 15, grp = lane >> 4;
    const long g0 = (long)blockIdx.x * MR;
    const int b = (int)(g0 / T);
    const int wb = w * 128;      // wave's 128-col slab

    // ---- phase A: LN(x) -> Abuf bf16
    {
        float4 lg0 = *(const float4*)&lg[lane*8], lg1 = *(const float4*)&lg[lane*8+4];
        float4 lb0 = *(const float4*)&lb[lane*8], lb1 = *(const float4*)&lb[lane*8+4];
        for (int rr = 0; rr < 16; ++rr){
            int r = w*16 + rr;
            const float* xp = &x[(size_t)(g0 + r)*D + lane*8];
            float4 v0 = *(const float4*)xp, v1 = *(const float4*)(xp+4);
            float s  = v0.x+v0.y+v0.z+v0.w + v1.x+v1.y+v1.z+v1.w;
            float sq = v0.x*v0.x+v0.y*v0.y+v0.z*v0.z+v0.w*v0.w
                     + v1.x*v1.x+v1.y*v1.y+v1.z*v1.z+v1.w*v1.w;
            #pragma unroll
            for (int o = 32; o; o >>= 1){ s += __shfl_xor(s,o); sq += __shfl_xor(sq,o); }
            float m = s*(1.f/D), var = sq*(1.f/D) - m*m, rstd = rsqrtf(var + 1e-5f);
            bf16x8 ov;
            ov[0] = (bf16)((v0.x-m)*rstd*lg0.x + lb0.x);
            ov[1] = (bf16)((v0.y-m)*rstd*lg0.y + lb0.y);
            ov[2] = (bf16)((v0.z-m)*rstd*lg0.z + lb0.z);
            ov[3] = (bf16)((v0.w-m)*rstd*lg0.w + lb0.w);
            ov[4] = (bf16)((v1.x-m)*rstd*lg1.x + lb1.x);
            ov[5] = (bf16)((v1.y-m)*rstd*lg1.y + lb1.y);
            ov[6] = (bf16)((v1.z-m)*rstd*lg1.z + lb1.z);
            ov[7] = (bf16)((v1.w-m)*rstd*lg1.w + lb1.w);
            *(bf16x8*)&Abuf[r*AS + lane*8] = ov;
        }
    }
    __syncthreads();

    // ---- phase B: q = LN(x) @ Wq   (acc fp32)
    f32x4 acc[4][8];
    #pragma unroll
    for (int mt = 0; mt < 4; ++mt)
        #pragma unroll
        for (int nt = 0; nt < 8; ++nt) acc[mt][nt] = (f32x4){0.f,0.f,0.f,0.f};
    gemm512(WqT, Abuf, wb, l15, grp, acc);

    // ---- phase C: +bq, per-(row,head) softmax over 64 (in-register)
    {
        float bqv[8];
        #pragma unroll
        for (int nt = 0; nt < 8; ++nt) bqv[nt] = bq[wb + nt*16 + l15];
        #pragma unroll
        for (int mt = 0; mt < 4; ++mt)
            #pragma unroll
            for (int r = 0; r < 4; ++r)
                #pragma unroll
                for (int hh = 0; hh < 2; ++hh){
                    float v0 = acc[mt][hh*4+0][r] + bqv[hh*4+0];
                    float v1 = acc[mt][hh*4+1][r] + bqv[hh*4+1];
                    float v2 = acc[mt][hh*4+2][r] + bqv[hh*4+2];
                    float v3 = acc[mt][hh*4+3][r] + bqv[hh*4+3];
                    float mx = fmaxf(fmaxf(v0,v1), fmaxf(v2,v3));
                    #pragma unroll
                    for (int o = 1; o < 16; o <<= 1) mx = fmaxf(mx, __shfl_xor(mx, o));
                    float e0 = __expf(v0-mx), e1 = __expf(v1-mx), e2 = __expf(v2-mx), e3 = __expf(v3-mx);
                    float sden = e0+e1+e2+e3;
                    #pragma unroll
                    for (int o = 1; o < 16; o <<= 1) sden += __shfl_xor(sden, o);
                    float inv = 1.f/sden;
                    acc[mt][hh*4+0][r] = e0*inv; acc[mt][hh*4+1][r] = e1*inv;
                    acc[mt][hh*4+2][r] = e2*inv; acc[mt][hh*4+3][r] = e3*inv;
                }
    }
    __syncthreads();            // all waves done reading Abuf (GEMM1) before overwrite

    // q (bf16) -> Abuf, wave-local region [all rows][own cols]
    #pragma unroll
    for (int mt = 0; mt < 4; ++mt)
        #pragma unroll
        for (int nt = 0; nt < 8; ++nt)
            #pragma unroll
            for (int r = 0; r < 4; ++r)
                Abuf[(mt*16 + grp*4 + r)*AS + wb + nt*16 + l15] = (bf16)acc[mt][nt][r];

    // ---- phase D: y = q @ att  (per-head 64x64, B from L2-hot attT)
    #pragma unroll
    for (int mt = 0; mt < 4; ++mt)
        #pragma unroll
        for (int nt = 0; nt < 8; ++nt) acc[mt][nt] = (f32x4){0.f,0.f,0.f,0.f};
    #pragma unroll
    for (int hh = 0; hh < 2; ++hh){
        const bf16* ab = attT + (((size_t)b*H + 2*w + hh) << 12);
        #pragma unroll
        for (int ks = 0; ks < 2; ++ks){
            bf16x8 qa[4];
            #pragma unroll
            for (int mt = 0; mt < 4; ++mt)
                qa[mt] = *(const bf16x8*)&Abuf[(mt*16 + l15)*AS + wb + hh*64 + ks*32 + grp*8];
            #pragma unroll
            for (int n4 = 0; n4 < 4; ++n4){
                bf16x8 bb = *(const bf16x8*)&ab[(size_t)(n4*16 + l15)*DH + ks*32 + grp*8];
                #pragma unroll
                for (int mt = 0; mt < 4; ++mt)
                    acc[mt][hh*4+n4] = __builtin_amdgcn_mfma_f32_16x16x32_bf16(qa[mt], bb, acc[mt][hh*4+n4], 0, 0, 0);
            }
        }
    }

    // ---- LN(y) stats: per-wave partials -> LDS -> combine
    #pragma unroll
    for (int mt = 0; mt < 4; ++mt)
        #pragma unroll
        for (int r = 0; r < 4; ++r){
            float s = 0.f, q2 = 0.f;
            #pragma unroll
            for (int nt = 0; nt < 8; ++nt){ float v = acc[mt][nt][r]; s += v; q2 += v*v; }
            #pragma unroll
            for (int o = 1; o < 16; o <<= 1){ s += __shfl_xor(s, o); q2 += __shfl_xor(q2, o); }
            if (l15 == 0){ st_s[mt*16 + grp*4 + r][w] = s; st_q[mt*16 + grp*4 + r][w] = q2; }
        }
    __syncthreads();

    // ---- stylize + silu -> Abuf bf16
    {
        float sgv[8], sbv[8], sscv[8], sshv[8];
        #pragma unroll
        for (int nt = 0; nt < 8; ++nt){
            int col = wb + nt*16 + l15;
            sgv[nt] = sg[col]; sbv[nt] = sb[col];
            sscv[nt] = ssb[b*1024 + col]; sshv[nt] = ssb[b*1024 + 512 + col];
        }
        #pragma unroll
        for (int mt = 0; mt < 4; ++mt)
            #pragma unroll
            for (int r = 0; r < 4; ++r){
                int row = mt*16 + grp*4 + r;
                float4 sv = *(const float4*)&st_s[row][0];
                float4 qv = *(const float4*)&st_q[row][0];
                float m = (sv.x+sv.y+sv.z+sv.w)*(1.f/D);
                float var = (qv.x+qv.y+qv.z+qv.w)*(1.f/D) - m*m;
                float rstd = rsqrtf(var + 1e-5f);
                #pragma unroll
                for (int nt = 0; nt < 8; ++nt){
                    float yn = (acc[mt][nt][r] - m)*rstd*sgv[nt] + sbv[nt];
                    float h2 = yn*(1.f + sscv[nt]) + sshv[nt];
                    Abuf[row*AS + wb + nt*16 + l15] = (bf16)(h2 * sigmoidf_(h2));
                }
            }
    }
    __syncthreads();            // h complete across all waves before GEMM2 reads full K

    // ---- phase E: out = silu(h) @ out_W + ob + x
    #pragma unroll
    for (int mt = 0; mt < 4; ++mt)
        #pragma unroll
        for (int nt = 0; nt < 8; ++nt) acc[mt][nt] = (f32x4){0.f,0.f,0.f,0.f};
    gemm512(oWT, Abuf, wb, l15, grp, acc);

    {
        float obv[8];
        #pragma unroll
        for (int nt = 0; nt < 8; ++nt) obv[nt] = ob[wb + nt*16 + l15];
        #pragma unroll
        for (int mt = 0; mt < 4; ++mt)
            #pragma unroll
            for (int r = 0; r < 4; ++r){
                size_t base = (size_t)(g0 + mt*16 + grp*4 + r)*D + wb + l15;
                #pragma unroll
                for (int nt = 0; nt < 8; ++nt){
                    size_t idx = base + nt*16;
                    out[idx] = acc[mt][nt][r] + obv[nt] + x[idx];
                }
            }
    }
}

extern "C" void kernel_launch(void* const* d_in, const int* in_sizes, int n_in,
                              void* d_out, int out_size, void* d_ws, size_t ws_size,
                              hipStream_t stream){
    const float* x     = (const float*)d_in[0];
    const float* xf    = (const float*)d_in[1];
    const float* emb   = (const float*)d_in[2];
    const float* Wq    = (const float*)d_in[3];
    const float* bq    = (const float*)d_in[4];
    const float* Wk    = (const float*)d_in[5];
    const float* bk    = (const float*)d_in[6];
    const float* Wv    = (const float*)d_in[7];
    const float* bv    = (const float*)d_in[8];
    const float* ln_g  = (const float*)d_in[9];
    const float* ln_b  = (const float*)d_in[10];
    const float* tln_g = (const float*)d_in[11];
    const float* tln_b = (const float*)d_in[12];
    const float* emb_W = (const float*)d_in[13];
    const float* emb_b = (const float*)d_in[14];
    const float* sn_g  = (const float*)d_in[15];
    const float* sn_b  = (const float*)d_in[16];
    const float* out_W = (const float*)d_in[17];
    const float* out_b = (const float*)d_in[18];
    float* out = (float*)d_out;

    // workspace carve (3.3 MB total, all 16B-aligned)
    float* ssb  = (float*)d_ws;                          // B*1024 f32
    bf16*  kbuf = (bf16*)(ssb + B*1024);                 // B*NN*D bf16
    bf16*  vbuf = kbuf + (size_t)B*NN*D;                 // B*NN*D bf16
    bf16*  attT = vbuf + (size_t)B*NN*D;                 // B*H*DH*DH bf16
    bf16*  wqT  = attT + (size_t)B*H*DH*DH;              // D*D bf16
    bf16*  owT  = wqT  + (size_t)D*D;                    // D*D bf16

    k_wprep<<<dim3(8,8),      dim3(256), 0, stream>>>(Wq,    wqT);
    k_wprep<<<dim3(8,8),      dim3(256), 0, stream>>>(out_W, owT);
    k_ss   <<<dim3(64, B),    dim3(256), 0, stream>>>(emb, emb_W, emb_b, ssb);
    k_kv   <<<dim3(B*NN/4),   dim3(256), 0, stream>>>(xf, Wk, bk, Wv, bv, tln_g, tln_b, kbuf, vbuf);
    k_att  <<<dim3(H, B),     dim3(256), 0, stream>>>(kbuf, vbuf, attT);
    k_main <<<dim3(B*T/MR),   dim3(256), 0, stream>>>(x, wqT, bq, ln_g, ln_b, attT, ssb,
                                                      sn_g, sn_b, owT, out_b, out);
}

// Round 4
// 215.523 us; speedup vs baseline: 3.1045x; 1.2017x over previous
//
#include <hip/hip_runtime.h>
#include <math.h>

#define B 4
#define T 8192
#define D 512
#define NN 256
#define L 768
#define TE 2048
#define H 8
#define DH 64
#define MR 64          // rows per k_main block
#define AS 520         // Abuf row stride in bf16

typedef __bf16 bf16;
typedef bf16  bf16x8 __attribute__((ext_vector_type(8)));
typedef float f32x4  __attribute__((ext_vector_type(4)));

__device__ __forceinline__ float sigmoidf_(float x){ return 1.0f/(1.0f+__expf(-x)); }

// ---------------- fused prep: [0,64) Wq^T, [64,128) out_W^T, [128,384) ss, [384,640) kv
__global__ __launch_bounds__(256) void k_prep(
    const float* __restrict__ Wq, const float* __restrict__ oW,
    bf16* __restrict__ wqT, bf16* __restrict__ owT,
    const float* __restrict__ emb, const float* __restrict__ emb_W,
    const float* __restrict__ emb_b, float* __restrict__ ss,
    const float* __restrict__ xf, const float* __restrict__ Wk,
    const float* __restrict__ bk, const float* __restrict__ Wv,
    const float* __restrict__ bv, const float* __restrict__ tg,
    const float* __restrict__ tb, bf16* __restrict__ kbuf, bf16* __restrict__ vbuf){
    __shared__ __align__(16) char smem[16640];
    const int bid = blockIdx.x, t = threadIdx.x;
    if (bid < 128){
        // weight transpose + bf16
        const float* W = (bid < 64) ? Wq : oW;
        bf16* Wt = (bid < 64) ? wqT : owT;
        int lb = bid & 63;
        float (*tile)[65] = (float(*)[65])smem;
        int k0 = (lb & 7)*64, n0 = (lb >> 3)*64;
        int c = t & 63, r4 = t >> 6;
        #pragma unroll
        for (int p = 0; p < 16; ++p){ int r = p*4 + r4; tile[r][c] = W[(size_t)(k0+r)*D + n0 + c]; }
        __syncthreads();
        #pragma unroll
        for (int p = 0; p < 16; ++p){ int n = p*4 + r4; Wt[(size_t)(n0+n)*D + k0 + c] = (bf16)tile[c][n]; }
    } else if (bid < 384){
        // ss = silu(emb) @ emb_W + emb_b
        float* semb = (float*)smem;
        float (*red)[17] = (float(*)[17])(smem + TE*4);
        int lb = bid - 128; int c = lb & 63, b = lb >> 6;
        for (int i = t; i < TE; i += 256){ float e = emb[b*TE + i]; semb[i] = e * sigmoidf_(e); }
        __syncthreads();
        int o = t & 15, p = t >> 4;
        int j = c*16 + o;
        float acc = 0.f;
        #pragma unroll 4
        for (int i = 0; i < TE/16; ++i){ int e = p*(TE/16) + i; acc += semb[e]*emb_W[e*1024 + j]; }
        red[p][o] = acc;
        __syncthreads();
        if (p == 0){
            float s = 0.f;
            #pragma unroll
            for (int pp = 0; pp < 16; ++pp) s += red[pp][o];
            ss[b*1024 + j] = s + emb_b[j];
        }
    } else {
        // kv: LN(xf) then k/v projections (bf16 out)
        float (*xfn)[L] = (float(*)[L])smem;
        int wave = t >> 6, lane = t & 63;
        int g0 = (bid - 384) * 4;
        {
            int g = g0 + wave;
            float vals[12];
            float s = 0.f, sq = 0.f;
            #pragma unroll
            for (int i = 0; i < 12; ++i){ float v = xf[(size_t)g*L + lane*12 + i]; vals[i] = v; s += v; sq += v*v; }
            #pragma unroll
            for (int o = 32; o; o >>= 1){ s += __shfl_xor(s, o); sq += __shfl_xor(sq, o); }
            float m = s / L; float var = sq / L - m*m;
            float rstd = rsqrtf(var + 1e-5f);
            #pragma unroll
            for (int i = 0; i < 12; ++i){
                int l = lane*12 + i;
                xfn[wave][l] = (vals[i]-m)*rstd*tg[l] + tb[l];
            }
        }
        __syncthreads();
        float ak[4][2] = {{0.f}}, av[4][2] = {{0.f}};
        for (int l = 0; l < L; l += 4){
            float4 xv[4];
            #pragma unroll
            for (int r = 0; r < 4; ++r) xv[r] = *(const float4*)&xfn[r][l];
            #pragma unroll
            for (int u = 0; u < 4; ++u){
                int lu = l + u;
                float wk0 = Wk[lu*D + t], wk1 = Wk[lu*D + t + 256];
                float wv0 = Wv[lu*D + t], wv1 = Wv[lu*D + t + 256];
                #pragma unroll
                for (int r = 0; r < 4; ++r){
                    float xr = ((const float*)&xv[r])[u];
                    ak[r][0] += xr*wk0; ak[r][1] += xr*wk1;
                    av[r][0] += xr*wv0; av[r][1] += xr*wv1;
                }
            }
        }
        float bk0 = bk[t], bk1 = bk[t+256], bv0 = bv[t], bv1 = bv[t+256];
        #pragma unroll
        for (int r = 0; r < 4; ++r){
            size_t g = (size_t)(g0 + r);
            kbuf[g*D + t]       = (bf16)(ak[r][0] + bk0);
            kbuf[g*D + t + 256] = (bf16)(ak[r][1] + bk1);
            vbuf[g*D + t]       = (bf16)(av[r][0] + bv0);
            vbuf[g*D + t + 256] = (bf16)(av[r][1] + bv1);
        }
    }
}

// ---------------- k-softmax over N; attT[b][h][l][d] = sum_n k_sm[n,d] v[n,l]  (bf16)
__global__ void k_att(const bf16* __restrict__ kbuf, const bf16* __restrict__ vbuf,
                      bf16* __restrict__ attT){
    __shared__ float kh[NN*DH];
    __shared__ float vh[NN*DH];
    __shared__ float pm[4][DH], ps[4][DH];
    int t = threadIdx.x, h = blockIdx.x, b = blockIdx.y;
    for (int k = 0; k < NN*DH/256; ++k){
        int m = k*256 + t;
        int n = m >> 6, dl = m & 63;
        size_t src = (size_t)(b*NN + n)*D + h*DH + dl;
        kh[m] = (float)kbuf[src]; vh[m] = (float)vbuf[src];
    }
    __syncthreads();
    int d = t & 63, c = t >> 6;            // 4 chunks of 64 tokens, parallel over d
    float mx = -1e30f;
    for (int n = c*64; n < c*64+64; ++n) mx = fmaxf(mx, kh[n*DH + d]);
    pm[c][d] = mx;
    __syncthreads();
    mx = fmaxf(fmaxf(pm[0][d], pm[1][d]), fmaxf(pm[2][d], pm[3][d]));
    float s = 0.f;
    for (int n = c*64; n < c*64+64; ++n){ float e = __expf(kh[n*DH + d] - mx); kh[n*DH + d] = e; s += e; }
    ps[c][d] = s;
    __syncthreads();
    float inv = 1.f/(ps[0][d] + ps[1][d] + ps[2][d] + ps[3][d]);
    for (int n = c*64; n < c*64+64; ++n) kh[n*DH + d] *= inv;
    __syncthreads();
    int dl = t >> 2, dd0 = (t & 3)*16;
    float acc[16] = {0.f};
    for (int n = 0; n < NN; ++n){
        float vv = vh[n*DH + dl];
        #pragma unroll
        for (int i = 0; i < 16; ++i) acc[i] += kh[n*DH + dd0 + i] * vv;
    }
    size_t base = (((size_t)b*H + h)*DH + dl)*DH + dd0;
    bf16x8 o0, o1;
    #pragma unroll
    for (int i = 0; i < 8; ++i){ o0[i] = (bf16)acc[i]; o1[i] = (bf16)acc[8+i]; }
    *(bf16x8*)&attT[base]     = o0;
    *(bf16x8*)&attT[base + 8] = o1;
}

// ---------------- MFMA GEMM: acc += A(64xD, LDS) * Wt([n][k] bf16, L2)
template<int MT, int NT>
__device__ __forceinline__ void gemm512(const bf16* __restrict__ Wt, const bf16* Ab,
                                        int wb, int l15, int grp, f32x4 (&acc)[MT][NT]){
    #pragma unroll
    for (int ks = 0; ks < 16; ++ks){
        bf16x8 aa[MT];
        #pragma unroll
        for (int mt = 0; mt < MT; ++mt)
            aa[mt] = *(const bf16x8*)&Ab[(mt*16 + l15)*AS + ks*32 + grp*8];
        #pragma unroll
        for (int nt = 0; nt < NT; ++nt){
            bf16x8 bb = *(const bf16x8*)&Wt[(size_t)(wb + nt*16 + l15)*D + ks*32 + grp*8];
            #pragma unroll
            for (int mt = 0; mt < MT; ++mt)
                acc[mt][nt] = __builtin_amdgcn_mfma_f32_16x16x32_bf16(aa[mt], bb, acc[mt][nt], 0, 0, 0);
        }
    }
}

// ---------------- main fused kernel: 64 rows/block, 8 waves (1 head each)
__global__ __launch_bounds__(512, 4) void k_main(
    const float* __restrict__ x, const bf16* __restrict__ WqT, const float* __restrict__ bq,
    const float* __restrict__ lg, const float* __restrict__ lb,
    const bf16* __restrict__ attT, const float* __restrict__ ssb,
    const float* __restrict__ sg, const float* __restrict__ sb,
    const bf16* __restrict__ oWT, const float* __restrict__ ob,
    float* __restrict__ out){
    __shared__ __align__(16) bf16 Abuf[MR*AS];   // 66.6 KB, reused LN(x)->q->silu(h)
    __shared__ float st_s[MR][8];
    __shared__ float st_q[MR][8];
    const int t = threadIdx.x, w = t >> 6, lane = t & 63;
    const int l15 = lane & 15, grp = lane >> 4;
    const long g0 = (long)blockIdx.x * MR;
    const int b = (int)(g0 / T);
    const int wb = w * 64;       // wave's 64-col slab == head w

    // ---- phase A: LN(x) -> Abuf bf16 (8 rows per wave)
    {
        float4 lg0 = *(const float4*)&lg[lane*8], lg1 = *(const float4*)&lg[lane*8+4];
        float4 lb0 = *(const float4*)&lb[lane*8], lb1 = *(const float4*)&lb[lane*8+4];
        #pragma unroll
        for (int rr = 0; rr < 8; ++rr){
            int r = w*8 + rr;
            const float* xp = &x[(size_t)(g0 + r)*D + lane*8];
            float4 v0 = *(const float4*)xp, v1 = *(const float4*)(xp+4);
            float s  = v0.x+v0.y+v0.z+v0.w + v1.x+v1.y+v1.z+v1.w;
            float sq = v0.x*v0.x+v0.y*v0.y+v0.z*v0.z+v0.w*v0.w
                     + v1.x*v1.x+v1.y*v1.y+v1.z*v1.z+v1.w*v1.w;
            #pragma unroll
            for (int o = 32; o; o >>= 1){ s += __shfl_xor(s,o); sq += __shfl_xor(sq,o); }
            float m = s*(1.f/D), var = sq*(1.f/D) - m*m, rstd = rsqrtf(var + 1e-5f);
            bf16x8 ov;
            ov[0] = (bf16)((v0.x-m)*rstd*lg0.x + lb0.x);
            ov[1] = (bf16)((v0.y-m)*rstd*lg0.y + lb0.y);
            ov[2] = (bf16)((v0.z-m)*rstd*lg0.z + lb0.z);
            ov[3] = (bf16)((v0.w-m)*rstd*lg0.w + lb0.w);
            ov[4] = (bf16)((v1.x-m)*rstd*lg1.x + lb1.x);
            ov[5] = (bf16)((v1.y-m)*rstd*lg1.y + lb1.y);
            ov[6] = (bf16)((v1.z-m)*rstd*lg1.z + lb1.z);
            ov[7] = (bf16)((v1.w-m)*rstd*lg1.w + lb1.w);
            *(bf16x8*)&Abuf[r*AS + lane*8] = ov;
        }
    }
    __syncthreads();

    // ---- phase B: q = LN(x) @ Wq
    f32x4 acc[4][4];
    #pragma unroll
    for (int mt = 0; mt < 4; ++mt)
        #pragma unroll
        for (int nt = 0; nt < 4; ++nt) acc[mt][nt] = (f32x4){0.f,0.f,0.f,0.f};
    gemm512<4,4>(WqT, Abuf, wb, l15, grp, acc);

    // ---- phase C: +bq, per-row softmax over this wave's head (64 dims)
    {
        float bqv[4];
        #pragma unroll
        for (int nt = 0; nt < 4; ++nt) bqv[nt] = bq[wb + nt*16 + l15];
        #pragma unroll
        for (int mt = 0; mt < 4; ++mt)
            #pragma unroll
            for (int r = 0; r < 4; ++r){
                float v0 = acc[mt][0][r] + bqv[0];
                float v1 = acc[mt][1][r] + bqv[1];
                float v2 = acc[mt][2][r] + bqv[2];
                float v3 = acc[mt][3][r] + bqv[3];
                float mx = fmaxf(fmaxf(v0,v1), fmaxf(v2,v3));
                #pragma unroll
                for (int o = 1; o < 16; o <<= 1) mx = fmaxf(mx, __shfl_xor(mx, o));
                float e0 = __expf(v0-mx), e1 = __expf(v1-mx), e2 = __expf(v2-mx), e3 = __expf(v3-mx);
                float sden = e0+e1+e2+e3;
                #pragma unroll
                for (int o = 1; o < 16; o <<= 1) sden += __shfl_xor(sden, o);
                float inv = 1.f/sden;
                acc[mt][0][r] = e0*inv; acc[mt][1][r] = e1*inv;
                acc[mt][2][r] = e2*inv; acc[mt][3][r] = e3*inv;
            }
    }
    __syncthreads();            // all waves done reading LN(x) before overwrite

    // q (bf16) -> Abuf [all 64 rows][own 64 cols]
    #pragma unroll
    for (int mt = 0; mt < 4; ++mt)
        #pragma unroll
        for (int nt = 0; nt < 4; ++nt)
            #pragma unroll
            for (int r = 0; r < 4; ++r)
                Abuf[(mt*16 + grp*4 + r)*AS + wb + nt*16 + l15] = (bf16)acc[mt][nt][r];
    __syncthreads();            // cross-lane q visibility within/between waves

    // ---- phase D: y = q @ att[head w]  (wave-local cols)
    #pragma unroll
    for (int mt = 0; mt < 4; ++mt)
        #pragma unroll
        for (int nt = 0; nt < 4; ++nt) acc[mt][nt] = (f32x4){0.f,0.f,0.f,0.f};
    {
        const bf16* ab = attT + (((size_t)b*H + w) << 12);
        #pragma unroll
        for (int ks = 0; ks < 2; ++ks){
            bf16x8 qa[4];
            #pragma unroll
            for (int mt = 0; mt < 4; ++mt)
                qa[mt] = *(const bf16x8*)&Abuf[(mt*16 + l15)*AS + wb + ks*32 + grp*8];
            #pragma unroll
            for (int n4 = 0; n4 < 4; ++n4){
                bf16x8 bb = *(const bf16x8*)&ab[(size_t)(n4*16 + l15)*DH + ks*32 + grp*8];
                #pragma unroll
                for (int mt = 0; mt < 4; ++mt)
                    acc[mt][n4] = __builtin_amdgcn_mfma_f32_16x16x32_bf16(qa[mt], bb, acc[mt][n4], 0, 0, 0);
            }
        }
    }

    // ---- LN(y) stats: per-wave partials -> LDS -> combine
    #pragma unroll
    for (int mt = 0; mt < 4; ++mt)
        #pragma unroll
        for (int r = 0; r < 4; ++r){
            float s = 0.f, q2 = 0.f;
            #pragma unroll
            for (int nt = 0; nt < 4; ++nt){ float v = acc[mt][nt][r]; s += v; q2 += v*v; }
            #pragma unroll
            for (int o = 1; o < 16; o <<= 1){ s += __shfl_xor(s, o); q2 += __shfl_xor(q2, o); }
            if (l15 == 0){ st_s[mt*16 + grp*4 + r][w] = s; st_q[mt*16 + grp*4 + r][w] = q2; }
        }
    __syncthreads();

    // ---- stylize + silu -> Abuf bf16
    {
        float sgv[4], sbv[4], sscv[4], sshv[4];
        #pragma unroll
        for (int nt = 0; nt < 4; ++nt){
            int col = wb + nt*16 + l15;
            sgv[nt] = sg[col]; sbv[nt] = sb[col];
            sscv[nt] = ssb[b*1024 + col]; sshv[nt] = ssb[b*1024 + 512 + col];
        }
        #pragma unroll
        for (int mt = 0; mt < 4; ++mt)
            #pragma unroll
            for (int r = 0; r < 4; ++r){
                int row = mt*16 + grp*4 + r;
                float4 s0 = *(const float4*)&st_s[row][0];
                float4 s1 = *(const float4*)&st_s[row][4];
                float4 q0 = *(const float4*)&st_q[row][0];
                float4 q1 = *(const float4*)&st_q[row][4];
                float m = (s0.x+s0.y+s0.z+s0.w + s1.x+s1.y+s1.z+s1.w)*(1.f/D);
                float var = (q0.x+q0.y+q0.z+q0.w + q1.x+q1.y+q1.z+q1.w)*(1.f/D) - m*m;
                float rstd = rsqrtf(var + 1e-5f);
                #pragma unroll
                for (int nt = 0; nt < 4; ++nt){
                    float yn = (acc[mt][nt][r] - m)*rstd*sgv[nt] + sbv[nt];
                    float h2 = yn*(1.f + sscv[nt]) + sshv[nt];
                    Abuf[row*AS + wb + nt*16 + l15] = (bf16)(h2 * sigmoidf_(h2));
                }
            }
    }
    __syncthreads();            // h complete before GEMM2 reads full K

    // ---- phase E: out = silu(h) @ out_W + ob + x
    #pragma unroll
    for (int mt = 0; mt < 4; ++mt)
        #pragma unroll
        for (int nt = 0; nt < 4; ++nt) acc[mt][nt] = (f32x4){0.f,0.f,0.f,0.f};
    gemm512<4,4>(oWT, Abuf, wb, l15, grp, acc);

    {
        float obv[4];
        #pragma unroll
        for (int nt = 0; nt < 4; ++nt) obv[nt] = ob[wb + nt*16 + l15];
        #pragma unroll
        for (int mt = 0; mt < 4; ++mt)
            #pragma unroll
            for (int r = 0; r < 4; ++r){
                size_t base = (size_t)(g0 + mt*16 + grp*4 + r)*D + wb + l15;
                #pragma unroll
                for (int nt = 0; nt < 4; ++nt){
                    size_t idx = base + nt*16;
                    out[idx] = acc[mt][nt][r] + obv[nt] + x[idx];
                }
            }
    }
}

extern "C" void kernel_launch(void* const* d_in, const int* in_sizes, int n_in,
                              void* d_out, int out_size, void* d_ws, size_t ws_size,
                              hipStream_t stream){
    const float* x     = (const float*)d_in[0];
    const float* xf    = (const float*)d_in[1];
    const float* emb   = (const float*)d_in[2];
    const float* Wq    = (const float*)d_in[3];
    const float* bq    = (const float*)d_in[4];
    const float* Wk    = (const float*)d_in[5];
    const float* bk    = (const float*)d_in[6];
    const float* Wv    = (const float*)d_in[7];
    const float* bv    = (const float*)d_in[8];
    const float* ln_g  = (const float*)d_in[9];
    const float* ln_b  = (const float*)d_in[10];
    const float* tln_g = (const float*)d_in[11];
    const float* tln_b = (const float*)d_in[12];
    const float* emb_W = (const float*)d_in[13];
    const float* emb_b = (const float*)d_in[14];
    const float* sn_g  = (const float*)d_in[15];
    const float* sn_b  = (const float*)d_in[16];
    const float* out_W = (const float*)d_in[17];
    const float* out_b = (const float*)d_in[18];
    float* out = (float*)d_out;

    // workspace carve
    float* ssb  = (float*)d_ws;                          // B*1024 f32
    bf16*  kbuf = (bf16*)(ssb + B*1024);                 // B*NN*D bf16
    bf16*  vbuf = kbuf + (size_t)B*NN*D;                 // B*NN*D bf16
    bf16*  attT = vbuf + (size_t)B*NN*D;                 // B*H*DH*DH bf16
    bf16*  wqT  = attT + (size_t)B*H*DH*DH;              // D*D bf16
    bf16*  owT  = wqT  + (size_t)D*D;                    // D*D bf16

    k_prep<<<dim3(640),    dim3(256), 0, stream>>>(Wq, out_W, wqT, owT,
                                                   emb, emb_W, emb_b, ssb,
                                                   xf, Wk, bk, Wv, bv, tln_g, tln_b, kbuf, vbuf);
    k_att <<<dim3(H, B),   dim3(256), 0, stream>>>(kbuf, vbuf, attT);
    k_main<<<dim3(B*T/MR), dim3(512), 0, stream>>>(x, wqT, bq, ln_g, ln_b, attT, ssb,
                                                   sn_g, sn_b, owT, out_b, out);
}

// Round 5
// 184.187 us; speedup vs baseline: 3.6327x; 1.1701x over previous
//
#include <hip/hip_runtime.h>
#include <math.h>
#include <stdint.h>

#define B 4
#define T 8192
#define D 512
#define NN 256
#define L 768
#define TE 2048
#define H 8
#define DH 64
#define MR 64
#define AS 520          // Abuf row stride (bf16 elems)
#define SLICE 16384     // elems per 32-K staged B slice (512 cols * 32 k)

typedef __bf16 bf16;
typedef bf16  bf16x8 __attribute__((ext_vector_type(8)));
typedef float f32x4  __attribute__((ext_vector_type(4)));

__device__ __forceinline__ float sigmoidf_(float x){ return 1.0f/(1.0f+__expf(-x)); }

__device__ __forceinline__ void load_lds16(const bf16* g, bf16* l){
    __builtin_amdgcn_global_load_lds((const __attribute__((address_space(1))) uint32_t*)g,
                                     (__attribute__((address_space(3))) uint32_t*)l, 16, 0, 0);
}

// ======== fused prep ========
// [0,128): weight re-layout  W (f32 [k][n]) -> Wst bf16 [kk][col][k']  (kk = k/32)
// [128,192): ss = silu(emb) @ emb_W + emb_b (all 4 batches per block)
// [192,448): kv: LN(xf) + k/v projection; block = (16-row group) x (128-col quarter)
__global__ __launch_bounds__(256) void k_prep(
    const float* __restrict__ Wq, const float* __restrict__ oW,
    bf16* __restrict__ wqS, bf16* __restrict__ owS,
    const float* __restrict__ emb, const float* __restrict__ emb_W,
    const float* __restrict__ emb_b, float* __restrict__ ss,
    const float* __restrict__ xf, const float* __restrict__ Wk,
    const float* __restrict__ bk, const float* __restrict__ Wv,
    const float* __restrict__ bv, const float* __restrict__ tg,
    const float* __restrict__ tb, bf16* __restrict__ kbuf, bf16* __restrict__ vbuf){
    __shared__ __align__(16) char smem[49408];
    const int bid = blockIdx.x, t = threadIdx.x;
    if (bid < 128){
        const float* W = (bid < 64) ? Wq : oW;
        bf16* Wst = (bid < 64) ? wqS : owS;
        int lb = bid & 63;
        int k0 = (lb & 7)*64, n0 = (lb >> 3)*64;
        float (*tile)[65] = (float(*)[65])smem;
        int c = t & 63, r4 = t >> 6;
        #pragma unroll
        for (int p = 0; p < 16; ++p){ int r = p*4 + r4; tile[r][c] = W[(size_t)(k0+r)*D + n0 + c]; }
        __syncthreads();
        int oct = t >> 6, col = t & 63;
        #pragma unroll
        for (int half = 0; half < 2; ++half){
            int kk = (lb & 7)*2 + half;
            bf16x8 ov;
            #pragma unroll
            for (int j = 0; j < 8; ++j) ov[j] = (bf16)tile[half*32 + oct*8 + j][col];
            *(bf16x8*)&Wst[(size_t)kk*SLICE + (n0+col)*32 + oct*8] = ov;
        }
    } else if (bid < 192){
        // ss for all 4 batches; block owns 16 output cols (c*16..)
        float (*semb)[TE] = (float(*)[TE])smem;                 // 4*2048*4 = 32KB
        float (*red)[64]  = (float(*)[64])(smem + 4*TE*4);      // 16*64*4  = 4KB
        int c = bid - 128;
        for (int i = t; i < TE; i += 256)
            #pragma unroll
            for (int b = 0; b < B; ++b){ float e = emb[b*TE + i]; semb[b][i] = e * sigmoidf_(e); }
        __syncthreads();
        int o = t & 15, p = t >> 4;
        int j = c*16 + o;
        float acc[B] = {0.f,0.f,0.f,0.f};
        for (int i = 0; i < 128; ++i){
            int e = p*128 + i;
            float wv = emb_W[(size_t)e*1024 + j];
            #pragma unroll
            for (int b = 0; b < B; ++b) acc[b] += semb[b][e] * wv;
        }
        #pragma unroll
        for (int b = 0; b < B; ++b) red[p][b*16 + o] = acc[b];
        __syncthreads();
        if (t < 64){
            int b = t >> 4, o2 = t & 15;
            int j2 = c*16 + o2;
            float s = 0.f;
            #pragma unroll
            for (int pp = 0; pp < 16; ++pp) s += red[pp][b*16 + o2];
            ss[b*1024 + j2] = s + emb_b[j2];
        }
    } else {
        // kv: 16 rows, 128-col quarter (k for t<128, v for t>=128)
        float (*xfn)[L] = (float(*)[L])smem;                    // 16*768*4 = 48KB
        int lb = bid - 192;
        int g0 = (lb >> 2) * 16, jc = lb & 3;
        int wave = t >> 6, lane = t & 63;
        #pragma unroll
        for (int rr = 0; rr < 4; ++rr){
            int r = wave*4 + rr, g = g0 + r;
            float vals[12];
            float s = 0.f, sq = 0.f;
            #pragma unroll
            for (int i = 0; i < 12; ++i){ float v = xf[(size_t)g*L + lane*12 + i]; vals[i] = v; s += v; sq += v*v; }
            #pragma unroll
            for (int o = 32; o; o >>= 1){ s += __shfl_xor(s, o); sq += __shfl_xor(sq, o); }
            float m = s / L; float var = sq / L - m*m;
            float rstd = rsqrtf(var + 1e-5f);
            #pragma unroll
            for (int i = 0; i < 12; ++i){
                int l = lane*12 + i;
                xfn[r][l] = (vals[i]-m)*rstd*tg[l] + tb[l];
            }
        }
        __syncthreads();
        const float* Wm = (t < 128) ? Wk : Wv;
        int col = jc*128 + (t & 127);
        float acc[16];
        #pragma unroll
        for (int r = 0; r < 16; ++r) acc[r] = 0.f;
        for (int l = 0; l < L; l += 4){
            float4 xv[16];
            #pragma unroll
            for (int r = 0; r < 16; ++r) xv[r] = *(const float4*)&xfn[r][l];
            #pragma unroll
            for (int u = 0; u < 4; ++u){
                float wv = Wm[(size_t)(l+u)*D + col];
                #pragma unroll
                for (int r = 0; r < 16; ++r) acc[r] += ((const float*)&xv[r])[u] * wv;
            }
        }
        float bias = (t < 128) ? bk[col] : bv[col];
        bf16* dst = (t < 128) ? kbuf : vbuf;
        #pragma unroll
        for (int r = 0; r < 16; ++r){
            size_t g = (size_t)(g0 + r);
            dst[g*D + col] = (bf16)(acc[r] + bias);
        }
    }
}

// ======== k-softmax over N; attF = fragment-ordered per-head state (bf16) ========
__global__ void k_att(const bf16* __restrict__ kbuf, const bf16* __restrict__ vbuf,
                      bf16* __restrict__ attF){
    __shared__ float kh[NN*DH];
    __shared__ float vh[NN*DH];
    __shared__ float pm[4][DH], ps[4][DH];
    int t = threadIdx.x, h = blockIdx.x, b = blockIdx.y;
    for (int k = 0; k < NN*DH/256; ++k){
        int m = k*256 + t;
        int n = m >> 6, dl = m & 63;
        size_t src = (size_t)(b*NN + n)*D + h*DH + dl;
        kh[m] = (float)kbuf[src]; vh[m] = (float)vbuf[src];
    }
    __syncthreads();
    int d = t & 63, c = t >> 6;
    float mx = -1e30f;
    for (int n = c*64; n < c*64+64; ++n) mx = fmaxf(mx, kh[n*DH + d]);
    pm[c][d] = mx;
    __syncthreads();
    mx = fmaxf(fmaxf(pm[0][d], pm[1][d]), fmaxf(pm[2][d], pm[3][d]));
    float s = 0.f;
    for (int n = c*64; n < c*64+64; ++n){ float e = __expf(kh[n*DH + d] - mx); kh[n*DH + d] = e; s += e; }
    ps[c][d] = s;
    __syncthreads();
    float inv = 1.f/(ps[0][d] + ps[1][d] + ps[2][d] + ps[3][d]);
    for (int n = c*64; n < c*64+64; ++n) kh[n*DH + d] *= inv;
    __syncthreads();
    int l = t >> 2, dd0 = (t & 3)*16;
    float acc[16];
    #pragma unroll
    for (int i = 0; i < 16; ++i) acc[i] = 0.f;
    for (int n = 0; n < NN; ++n){
        float vv = vh[n*DH + l];
        #pragma unroll
        for (int i = 0; i < 16; ++i) acc[i] += kh[n*DH + dd0 + i] * vv;
    }
    // fragment-ordered write: elem = hbase + f*512 + lane*8, f = (l>>4)*2 + (d0>>5),
    // lane = ((d0>>3)&3)*16 + (l&15); contents att[l][d0..d0+7]
    size_t hbase = ((size_t)(b*H + h)) << 12;
    #pragma unroll
    for (int half = 0; half < 2; ++half){
        int d0 = dd0 + half*8;
        int f  = (l >> 4)*2 + (d0 >> 5);
        int ln = ((d0 >> 3) & 3)*16 + (l & 15);
        bf16x8 ov;
        #pragma unroll
        for (int j = 0; j < 8; ++j) ov[j] = (bf16)acc[half*8 + j];
        *(bf16x8*)&attF[hbase + f*512 + ln*8] = ov;
    }
}

// ======== barrier-free staged GEMM over K=512 (16 slices of 32) ========
// Each wave stages ONLY its own 64-col chunk and reads ONLY that chunk -> no
// cross-wave LDS hazard; pipeline via counted vmcnt. Slice 0 must be staged
// (issued) before entry.
__device__ __forceinline__ void gemm_staged(const bf16* __restrict__ Wst, const bf16* Ab,
                                            bf16* Bb, int w, int lane, int l15, int grp,
                                            int wb, f32x4 (&acc)[4][4]){
    #pragma unroll
    for (int kk = 0; kk < 16; ++kk){
        const int cur = kk & 1;
        if (kk + 1 < 16){
            const bf16* src = Wst + (size_t)(kk+1)*SLICE + w*2048 + lane*8;
            bf16* dst = Bb + (cur^1)*SLICE + w*2048;
            #pragma unroll
            for (int c = 0; c < 4; ++c) load_lds16(src + c*512, dst + c*512);
            asm volatile("s_waitcnt vmcnt(4)" ::: "memory");   // slice kk landed
        } else {
            asm volatile("s_waitcnt vmcnt(0)" ::: "memory");
        }
        bf16x8 aa[4], bb4[4];
        #pragma unroll
        for (int mt = 0; mt < 4; ++mt)
            aa[mt] = *(const bf16x8*)&Ab[(mt*16 + l15)*AS + kk*32 + grp*8];
        #pragma unroll
        for (int nt = 0; nt < 4; ++nt)
            bb4[nt] = *(const bf16x8*)&Bb[cur*SLICE + (wb + nt*16 + l15)*32 + grp*8];
        #pragma unroll
        for (int nt = 0; nt < 4; ++nt)
            #pragma unroll
            for (int mt = 0; mt < 4; ++mt)
                acc[mt][nt] = __builtin_amdgcn_mfma_f32_16x16x32_bf16(aa[mt], bb4[nt], acc[mt][nt], 0, 0, 0);
    }
}

// ======== main fused kernel: 64 rows/block, 8 waves (1 head each), 1 block/CU ========
__global__ __launch_bounds__(512, 2) void k_main(
    const float* __restrict__ x, const bf16* __restrict__ WqS, const float* __restrict__ bq,
    const float* __restrict__ lg, const float* __restrict__ lb,
    const bf16* __restrict__ attF, const float* __restrict__ ssb,
    const float* __restrict__ sg, const float* __restrict__ sb,
    const bf16* __restrict__ oWS, const float* __restrict__ ob,
    float* __restrict__ out){
    __shared__ __align__(16) bf16 Abuf[MR*AS];      // 66.6 KB: LN(x) -> q -> silu(h)
    __shared__ __align__(16) bf16 Bbuf[2*SLICE];    // 64 KB: staged weight slices
    __shared__ float st_s[MR][8];
    __shared__ float st_q[MR][8];
    const int t = threadIdx.x, w = t >> 6, lane = t & 63;
    const int l15 = lane & 15, grp = lane >> 4;
    const long g0 = (long)blockIdx.x * MR;
    const int b = (int)(g0 / T);
    const int wb = w * 64;

    // stage GEMM1 slice 0 (overlaps with LN phase)
    {
        const bf16* src = WqS + w*2048 + lane*8;
        bf16* dst = &Bbuf[w*2048];
        #pragma unroll
        for (int c = 0; c < 4; ++c) load_lds16(src + c*512, dst + c*512);
    }

    // ---- phase A: LN(x) -> Abuf bf16 (8 rows per wave)
    {
        float4 lg0 = *(const float4*)&lg[lane*8], lg1 = *(const float4*)&lg[lane*8+4];
        float4 lb0 = *(const float4*)&lb[lane*8], lb1 = *(const float4*)&lb[lane*8+4];
        #pragma unroll
        for (int rr = 0; rr < 8; ++rr){
            int r = w*8 + rr;
            const float* xp = &x[(size_t)(g0 + r)*D + lane*8];
            float4 v0 = *(const float4*)xp, v1 = *(const float4*)(xp+4);
            float s  = v0.x+v0.y+v0.z+v0.w + v1.x+v1.y+v1.z+v1.w;
            float sq = v0.x*v0.x+v0.y*v0.y+v0.z*v0.z+v0.w*v0.w
                     + v1.x*v1.x+v1.y*v1.y+v1.z*v1.z+v1.w*v1.w;
            #pragma unroll
            for (int o = 32; o; o >>= 1){ s += __shfl_xor(s,o); sq += __shfl_xor(sq,o); }
            float m = s*(1.f/D), var = sq*(1.f/D) - m*m, rstd = rsqrtf(var + 1e-5f);
            bf16x8 ov;
            ov[0] = (bf16)((v0.x-m)*rstd*lg0.x + lb0.x);
            ov[1] = (bf16)((v0.y-m)*rstd*lg0.y + lb0.y);
            ov[2] = (bf16)((v0.z-m)*rstd*lg0.z + lb0.z);
            ov[3] = (bf16)((v0.w-m)*rstd*lg0.w + lb0.w);
            ov[4] = (bf16)((v1.x-m)*rstd*lg1.x + lb1.x);
            ov[5] = (bf16)((v1.y-m)*rstd*lg1.y + lb1.y);
            ov[6] = (bf16)((v1.z-m)*rstd*lg1.z + lb1.z);
            ov[7] = (bf16)((v1.w-m)*rstd*lg1.w + lb1.w);
            *(bf16x8*)&Abuf[r*AS + lane*8] = ov;
        }
    }
    __syncthreads();   // LN visible to all; stage0 drained by barrier's vmcnt(0)

    // ---- GEMM1: q = LN(x) @ Wq
    f32x4 acc[4][4];
    #pragma unroll
    for (int mt = 0; mt < 4; ++mt)
        #pragma unroll
        for (int nt = 0; nt < 4; ++nt) acc[mt][nt] = (f32x4){0.f,0.f,0.f,0.f};
    gemm_staged(WqS, Abuf, Bbuf, w, lane, l15, grp, wb, acc);

    // stage GEMM2 slice 0 now (lands during softmax / attn)
    {
        const bf16* src = oWS + w*2048 + lane*8;
        bf16* dst = &Bbuf[w*2048];
        #pragma unroll
        for (int c = 0; c < 4; ++c) load_lds16(src + c*512, dst + c*512);
    }
    __syncthreads();   // all waves done reading Abuf (A of GEMM1) before overwrite

    // ---- softmax over this wave's head (in-register)
    {
        float bqv[4];
        #pragma unroll
        for (int nt = 0; nt < 4; ++nt) bqv[nt] = bq[wb + nt*16 + l15];
        #pragma unroll
        for (int mt = 0; mt < 4; ++mt)
            #pragma unroll
            for (int r = 0; r < 4; ++r){
                float v0 = acc[mt][0][r] + bqv[0];
                float v1 = acc[mt][1][r] + bqv[1];
                float v2 = acc[mt][2][r] + bqv[2];
                float v3 = acc[mt][3][r] + bqv[3];
                float mx = fmaxf(fmaxf(v0,v1), fmaxf(v2,v3));
                #pragma unroll
                for (int o = 1; o < 16; o <<= 1) mx = fmaxf(mx, __shfl_xor(mx, o));
                float e0 = __expf(v0-mx), e1 = __expf(v1-mx), e2 = __expf(v2-mx), e3 = __expf(v3-mx);
                float sden = e0+e1+e2+e3;
                #pragma unroll
                for (int o = 1; o < 16; o <<= 1) sden += __shfl_xor(sden, o);
                float inv = 1.f/sden;
                acc[mt][0][r] = e0*inv; acc[mt][1][r] = e1*inv;
                acc[mt][2][r] = e2*inv; acc[mt][3][r] = e3*inv;
            }
    }
    // q (bf16) -> Abuf [all 64 rows][own 64 cols]
    #pragma unroll
    for (int mt = 0; mt < 4; ++mt)
        #pragma unroll
        for (int nt = 0; nt < 4; ++nt)
            #pragma unroll
            for (int r = 0; r < 4; ++r)
                Abuf[(mt*16 + grp*4 + r)*AS + wb + nt*16 + l15] = (bf16)acc[mt][nt][r];
    __syncthreads();   // cross-lane q visibility (transposed lane mapping)

    // ---- phase D: y = q @ att[head w]  (B from L2, fragment-ordered = coalesced)
    #pragma unroll
    for (int mt = 0; mt < 4; ++mt)
        #pragma unroll
        for (int nt = 0; nt < 4; ++nt) acc[mt][nt] = (f32x4){0.f,0.f,0.f,0.f};
    {
        const bf16* ab = attF + (((size_t)b*H + w) << 12);
        bf16x8 bfr[2][4];
        #pragma unroll
        for (int ks = 0; ks < 2; ++ks)
            #pragma unroll
            for (int n4 = 0; n4 < 4; ++n4)
                bfr[ks][n4] = *(const bf16x8*)&ab[(n4*2 + ks)*512 + lane*8];
        #pragma unroll
        for (int ks = 0; ks < 2; ++ks){
            bf16x8 qa[4];
            #pragma unroll
            for (int mt = 0; mt < 4; ++mt)
                qa[mt] = *(const bf16x8*)&Abuf[(mt*16 + l15)*AS + wb + ks*32 + grp*8];
            #pragma unroll
            for (int n4 = 0; n4 < 4; ++n4)
                #pragma unroll
                for (int mt = 0; mt < 4; ++mt)
                    acc[mt][n4] = __builtin_amdgcn_mfma_f32_16x16x32_bf16(qa[mt], bfr[ks][n4], acc[mt][n4], 0, 0, 0);
        }
    }

    // ---- LN(y) stats: per-wave partials -> LDS -> combine
    #pragma unroll
    for (int mt = 0; mt < 4; ++mt)
        #pragma unroll
        for (int r = 0; r < 4; ++r){
            float s = 0.f, q2 = 0.f;
            #pragma unroll
            for (int nt = 0; nt < 4; ++nt){ float v = acc[mt][nt][r]; s += v; q2 += v*v; }
            #pragma unroll
            for (int o = 1; o < 16; o <<= 1){ s += __shfl_xor(s, o); q2 += __shfl_xor(q2, o); }
            if (l15 == 0){ st_s[mt*16 + grp*4 + r][w] = s; st_q[mt*16 + grp*4 + r][w] = q2; }
        }
    __syncthreads();

    // ---- stylize + silu -> Abuf bf16
    {
        float sgv[4], sbv[4], sscv[4], sshv[4];
        #pragma unroll
        for (int nt = 0; nt < 4; ++nt){
            int col = wb + nt*16 + l15;
            sgv[nt] = sg[col]; sbv[nt] = sb[col];
            sscv[nt] = ssb[b*1024 + col]; sshv[nt] = ssb[b*1024 + 512 + col];
        }
        #pragma unroll
        for (int mt = 0; mt < 4; ++mt)
            #pragma unroll
            for (int r = 0; r < 4; ++r){
                int row = mt*16 + grp*4 + r;
                float4 s0 = *(const float4*)&st_s[row][0];
                float4 s1 = *(const float4*)&st_s[row][4];
                float4 q0 = *(const float4*)&st_q[row][0];
                float4 q1 = *(const float4*)&st_q[row][4];
                float m = (s0.x+s0.y+s0.z+s0.w + s1.x+s1.y+s1.z+s1.w)*(1.f/D);
                float var = (q0.x+q0.y+q0.z+q0.w + q1.x+q1.y+q1.z+q1.w)*(1.f/D) - m*m;
                float rstd = rsqrtf(var + 1e-5f);
                #pragma unroll
                for (int nt = 0; nt < 4; ++nt){
                    float yn = (acc[mt][nt][r] - m)*rstd*sgv[nt] + sbv[nt];
                    float h2 = yn*(1.f + sscv[nt]) + sshv[nt];
                    Abuf[row*AS + wb + nt*16 + l15] = (bf16)(h2 * sigmoidf_(h2));
                }
            }
    }
    __syncthreads();   // h complete across all waves before GEMM2 reads full K

    // ---- GEMM2: out = silu(h) @ out_W + ob + x
    #pragma unroll
    for (int mt = 0; mt < 4; ++mt)
        #pragma unroll
        for (int nt = 0; nt < 4; ++nt) acc[mt][nt] = (f32x4){0.f,0.f,0.f,0.f};
    gemm_staged(oWS, Abuf, Bbuf, w, lane, l15, grp, wb, acc);

    {
        float obv[4];
        #pragma unroll
        for (int nt = 0; nt < 4; ++nt) obv[nt] = ob[wb + nt*16 + l15];
        #pragma unroll
        for (int mt = 0; mt < 4; ++mt)
            #pragma unroll
            for (int r = 0; r < 4; ++r){
                size_t base = (size_t)(g0 + mt*16 + grp*4 + r)*D + wb + l15;
                #pragma unroll
                for (int nt = 0; nt < 4; ++nt){
                    size_t idx = base + nt*16;
                    out[idx] = acc[mt][nt][r] + obv[nt] + x[idx];
                }
            }
    }
}

extern "C" void kernel_launch(void* const* d_in, const int* in_sizes, int n_in,
                              void* d_out, int out_size, void* d_ws, size_t ws_size,
                              hipStream_t stream){
    const float* x     = (const float*)d_in[0];
    const float* xf    = (const float*)d_in[1];
    const float* emb   = (const float*)d_in[2];
    const float* Wq    = (const float*)d_in[3];
    const float* bq    = (const float*)d_in[4];
    const float* Wk    = (const float*)d_in[5];
    const float* bk    = (const float*)d_in[6];
    const float* Wv    = (const float*)d_in[7];
    const float* bv    = (const float*)d_in[8];
    const float* ln_g  = (const float*)d_in[9];
    const float* ln_b  = (const float*)d_in[10];
    const float* tln_g = (const float*)d_in[11];
    const float* tln_b = (const float*)d_in[12];
    const float* emb_W = (const float*)d_in[13];
    const float* emb_b = (const float*)d_in[14];
    const float* sn_g  = (const float*)d_in[15];
    const float* sn_b  = (const float*)d_in[16];
    const float* out_W = (const float*)d_in[17];
    const float* out_b = (const float*)d_in[18];
    float* out = (float*)d_out;

    // workspace carve
    float* ssb  = (float*)d_ws;                          // B*1024 f32
    bf16*  kbuf = (bf16*)(ssb + B*1024);                 // B*NN*D bf16
    bf16*  vbuf = kbuf + (size_t)B*NN*D;                 // B*NN*D bf16
    bf16*  attF = vbuf + (size_t)B*NN*D;                 // B*H*DH*DH bf16
    bf16*  wqS  = attF + (size_t)B*H*DH*DH;              // D*D bf16 (staged layout)
    bf16*  owS  = wqS  + (size_t)D*D;                    // D*D bf16

    k_prep<<<dim3(448),    dim3(256), 0, stream>>>(Wq, out_W, wqS, owS,
                                                   emb, emb_W, emb_b, ssb,
                                                   xf, Wk, bk, Wv, bv, tln_g, tln_b, kbuf, vbuf);
    k_att <<<dim3(H, B),   dim3(256), 0, stream>>>(kbuf, vbuf, attF);
    k_main<<<dim3(B*T/MR), dim3(512), 0, stream>>>(x, wqS, bq, ln_g, ln_b, attF, ssb,
                                                   sn_g, sn_b, owS, out_b, out);
}

// Round 6
// 181.957 us; speedup vs baseline: 3.6772x; 1.0123x over previous
//
#include <hip/hip_runtime.h>
#include <math.h>
#include <stdint.h>

#define B 4
#define T 8192
#define D 512
#define NN 256
#define L 768
#define TE 2048
#define H 8
#define DH 64
#define MR 64
#define AS 520          // Abuf row stride (bf16 elems)
#define SLICE 16384     // elems per 32-K staged B slice (512 cols * 32 k)

typedef __bf16 bf16;
typedef bf16  bf16x8 __attribute__((ext_vector_type(8)));
typedef float f32x4  __attribute__((ext_vector_type(4)));

__device__ __forceinline__ float sigmoidf_(float x){ return 1.0f/(1.0f+__expf(-x)); }

// ======== fused prep ========
// [0,128): weight re-layout  W (f32 [k][n]) -> Wst bf16 [kk][col][k']  (kk = k/32)
// [128,192): ss = silu(emb) @ emb_W + emb_b (all 4 batches per block)
// [192,448): kv: LN(xf) + k/v projection; block = (16-row group) x (128-col quarter)
__global__ __launch_bounds__(256) void k_prep(
    const float* __restrict__ Wq, const float* __restrict__ oW,
    bf16* __restrict__ wqS, bf16* __restrict__ owS,
    const float* __restrict__ emb, const float* __restrict__ emb_W,
    const float* __restrict__ emb_b, float* __restrict__ ss,
    const float* __restrict__ xf, const float* __restrict__ Wk,
    const float* __restrict__ bk, const float* __restrict__ Wv,
    const float* __restrict__ bv, const float* __restrict__ tg,
    const float* __restrict__ tb, bf16* __restrict__ kbuf, bf16* __restrict__ vbuf){
    __shared__ __align__(16) char smem[49408];
    const int bid = blockIdx.x, t = threadIdx.x;
    if (bid < 128){
        const float* W = (bid < 64) ? Wq : oW;
        bf16* Wst = (bid < 64) ? wqS : owS;
        int lb = bid & 63;
        int k0 = (lb & 7)*64, n0 = (lb >> 3)*64;
        float (*tile)[65] = (float(*)[65])smem;
        int c = t & 63, r4 = t >> 6;
        #pragma unroll
        for (int p = 0; p < 16; ++p){ int r = p*4 + r4; tile[r][c] = W[(size_t)(k0+r)*D + n0 + c]; }
        __syncthreads();
        int oct = t >> 6, col = t & 63;
        #pragma unroll
        for (int half = 0; half < 2; ++half){
            int kk = (lb & 7)*2 + half;
            bf16x8 ov;
            #pragma unroll
            for (int j = 0; j < 8; ++j) ov[j] = (bf16)tile[half*32 + oct*8 + j][col];
            *(bf16x8*)&Wst[(size_t)kk*SLICE + (n0+col)*32 + oct*8] = ov;
        }
    } else if (bid < 192){
        // ss for all 4 batches; block owns 16 output cols (c*16..)
        float (*semb)[TE] = (float(*)[TE])smem;                 // 4*2048*4 = 32KB
        float (*red)[64]  = (float(*)[64])(smem + 4*TE*4);      // 16*64*4  = 4KB
        int c = bid - 128;
        for (int i = t; i < TE; i += 256)
            #pragma unroll
            for (int b = 0; b < B; ++b){ float e = emb[b*TE + i]; semb[b][i] = e * sigmoidf_(e); }
        __syncthreads();
        int o = t & 15, p = t >> 4;
        int j = c*16 + o;
        float acc[B] = {0.f,0.f,0.f,0.f};
        for (int i = 0; i < 128; ++i){
            int e = p*128 + i;
            float wv = emb_W[(size_t)e*1024 + j];
            #pragma unroll
            for (int b = 0; b < B; ++b) acc[b] += semb[b][e] * wv;
        }
        #pragma unroll
        for (int b = 0; b < B; ++b) red[p][b*16 + o] = acc[b];
        __syncthreads();
        if (t < 64){
            int b = t >> 4, o2 = t & 15;
            int j2 = c*16 + o2;
            float s = 0.f;
            #pragma unroll
            for (int pp = 0; pp < 16; ++pp) s += red[pp][b*16 + o2];
            ss[b*1024 + j2] = s + emb_b[j2];
        }
    } else {
        // kv: 16 rows, 128-col quarter (k for t<128, v for t>=128)
        float (*xfn)[L] = (float(*)[L])smem;                    // 16*768*4 = 48KB
        int lb = bid - 192;
        int g0 = (lb >> 2) * 16, jc = lb & 3;
        int wave = t >> 6, lane = t & 63;
        #pragma unroll
        for (int rr = 0; rr < 4; ++rr){
            int r = wave*4 + rr, g = g0 + r;
            float vals[12];
            float s = 0.f, sq = 0.f;
            #pragma unroll
            for (int i = 0; i < 12; ++i){ float v = xf[(size_t)g*L + lane*12 + i]; vals[i] = v; s += v; sq += v*v; }
            #pragma unroll
            for (int o = 32; o; o >>= 1){ s += __shfl_xor(s, o); sq += __shfl_xor(sq, o); }
            float m = s / L; float var = sq / L - m*m;
            float rstd = rsqrtf(var + 1e-5f);
            #pragma unroll
            for (int i = 0; i < 12; ++i){
                int l = lane*12 + i;
                xfn[r][l] = (vals[i]-m)*rstd*tg[l] + tb[l];
            }
        }
        __syncthreads();
        const float* Wm = (t < 128) ? Wk : Wv;
        int col = jc*128 + (t & 127);
        float acc[16];
        #pragma unroll
        for (int r = 0; r < 16; ++r) acc[r] = 0.f;
        for (int l = 0; l < L; l += 4){
            float4 xv[16];
            #pragma unroll
            for (int r = 0; r < 16; ++r) xv[r] = *(const float4*)&xfn[r][l];
            #pragma unroll
            for (int u = 0; u < 4; ++u){
                float wv = Wm[(size_t)(l+u)*D + col];
                #pragma unroll
                for (int r = 0; r < 16; ++r) acc[r] += ((const float*)&xv[r])[u] * wv;
            }
        }
        float bias = (t < 128) ? bk[col] : bv[col];
        bf16* dst = (t < 128) ? kbuf : vbuf;
        #pragma unroll
        for (int r = 0; r < 16; ++r){
            size_t g = (size_t)(g0 + r);
            dst[g*D + col] = (bf16)(acc[r] + bias);
        }
    }
}

// ======== k-softmax over N; attF = fragment-ordered per-head state (bf16) ========
__global__ void k_att(const bf16* __restrict__ kbuf, const bf16* __restrict__ vbuf,
                      bf16* __restrict__ attF){
    __shared__ float kh[NN*DH];
    __shared__ float vh[NN*DH];
    __shared__ float pm[4][DH], ps[4][DH];
    int t = threadIdx.x, h = blockIdx.x, b = blockIdx.y;
    for (int k = 0; k < NN*DH/256; ++k){
        int m = k*256 + t;
        int n = m >> 6, dl = m & 63;
        size_t src = (size_t)(b*NN + n)*D + h*DH + dl;
        kh[m] = (float)kbuf[src]; vh[m] = (float)vbuf[src];
    }
    __syncthreads();
    int d = t & 63, c = t >> 6;
    float mx = -1e30f;
    for (int n = c*64; n < c*64+64; ++n) mx = fmaxf(mx, kh[n*DH + d]);
    pm[c][d] = mx;
    __syncthreads();
    mx = fmaxf(fmaxf(pm[0][d], pm[1][d]), fmaxf(pm[2][d], pm[3][d]));
    float s = 0.f;
    for (int n = c*64; n < c*64+64; ++n){ float e = __expf(kh[n*DH + d] - mx); kh[n*DH + d] = e; s += e; }
    ps[c][d] = s;
    __syncthreads();
    float inv = 1.f/(ps[0][d] + ps[1][d] + ps[2][d] + ps[3][d]);
    for (int n = c*64; n < c*64+64; ++n) kh[n*DH + d] *= inv;
    __syncthreads();
    int l = t >> 2, dd0 = (t & 3)*16;
    float acc[16];
    #pragma unroll
    for (int i = 0; i < 16; ++i) acc[i] = 0.f;
    for (int n = 0; n < NN; ++n){
        float vv = vh[n*DH + l];
        #pragma unroll
        for (int i = 0; i < 16; ++i) acc[i] += kh[n*DH + dd0 + i] * vv;
    }
    // fragment-ordered write: elem = hbase + f*512 + lane*8, f = (l>>4)*2 + (d0>>5),
    // lane = ((d0>>3)&3)*16 + (l&15); contents att[l][d0..d0+7]
    size_t hbase = ((size_t)(b*H + h)) << 12;
    #pragma unroll
    for (int half = 0; half < 2; ++half){
        int d0 = dd0 + half*8;
        int f  = (l >> 4)*2 + (d0 >> 5);
        int ln = ((d0 >> 3) & 3)*16 + (l & 15);
        bf16x8 ov;
        #pragma unroll
        for (int j = 0; j < 8; ++j) ov[j] = (bf16)acc[half*8 + j];
        *(bf16x8*)&attF[hbase + f*512 + ln*8] = ov;
    }
}

// ======== register-prefetched GEMM over K=512 (16 slices of 32, depth-2) ========
// B never touches LDS: per wave, slice frags (4 x bf16x8 = 16 VGPR) are loaded
// from the staged layout 2 slices ahead; compiler inserts counted vmcnt waits.
__device__ __forceinline__ void pf2(const bf16* __restrict__ base, bf16x8 (&bpre)[2][4]){
    #pragma unroll
    for (int s = 0; s < 2; ++s)
        #pragma unroll
        for (int nt = 0; nt < 4; ++nt)
            bpre[s][nt] = *(const bf16x8*)&base[(size_t)s*SLICE + nt*512];
}

__device__ __forceinline__ void gemm_body(const bf16* __restrict__ base, const bf16* Ab,
                                          int l15, int grp, bf16x8 (&bpre)[2][4],
                                          f32x4 (&acc)[4][4]){
    #pragma unroll
    for (int kk = 0; kk < 16; ++kk){
        bf16x8 bb[4];
        #pragma unroll
        for (int nt = 0; nt < 4; ++nt) bb[nt] = bpre[kk & 1][nt];
        if (kk + 2 < 16){
            #pragma unroll
            for (int nt = 0; nt < 4; ++nt)
                bpre[kk & 1][nt] = *(const bf16x8*)&base[(size_t)(kk+2)*SLICE + nt*512];
        }
        bf16x8 aa[4];
        #pragma unroll
        for (int mt = 0; mt < 4; ++mt)
            aa[mt] = *(const bf16x8*)&Ab[(mt*16 + l15)*AS + kk*32 + grp*8];
        #pragma unroll
        for (int nt = 0; nt < 4; ++nt)
            #pragma unroll
            for (int mt = 0; mt < 4; ++mt)
                acc[mt][nt] = __builtin_amdgcn_mfma_f32_16x16x32_bf16(aa[mt], bb[nt], acc[mt][nt], 0, 0, 0);
    }
}

// ======== main fused kernel: 64 rows/block, 8 waves (1 head each), 2 blocks/CU ========
__global__ __launch_bounds__(512, 4) void k_main(
    const float* __restrict__ x, const bf16* __restrict__ WqS, const float* __restrict__ bq,
    const float* __restrict__ lg, const float* __restrict__ lb,
    const bf16* __restrict__ attF, const float* __restrict__ ssb,
    const float* __restrict__ sg, const float* __restrict__ sb,
    const bf16* __restrict__ oWS, const float* __restrict__ ob,
    float* __restrict__ out){
    __shared__ __align__(16) bf16 Abuf[MR*AS];      // 66.6 KB: LN(x) -> q -> silu(h)
    __shared__ float st_s[MR][8];
    __shared__ float st_q[MR][8];
    const int t = threadIdx.x, w = t >> 6, lane = t & 63;
    const int l15 = lane & 15, grp = lane >> 4;
    const long g0 = (long)blockIdx.x * MR;
    const int b = (int)(g0 / T);
    const int wb = w * 64;
    // per-wave fragment base into staged weights: own 64-col chunk, own lane's 16B
    const size_t fragoff = (size_t)w*2048 + (size_t)l15*32 + (size_t)grp*8;

    // issue GEMM1 slices 0,1 now: they land during the LN phase
    bf16x8 bpre[2][4];
    pf2(WqS + fragoff, bpre);

    // ---- phase A: LN(x) -> Abuf bf16 (8 rows per wave)
    {
        float4 lg0 = *(const float4*)&lg[lane*8], lg1 = *(const float4*)&lg[lane*8+4];
        float4 lb0 = *(const float4*)&lb[lane*8], lb1 = *(const float4*)&lb[lane*8+4];
        #pragma unroll
        for (int rr = 0; rr < 8; ++rr){
            int r = w*8 + rr;
            const float* xp = &x[(size_t)(g0 + r)*D + lane*8];
            float4 v0 = *(const float4*)xp, v1 = *(const float4*)(xp+4);
            float s  = v0.x+v0.y+v0.z+v0.w + v1.x+v1.y+v1.z+v1.w;
            float sq = v0.x*v0.x+v0.y*v0.y+v0.z*v0.z+v0.w*v0.w
                     + v1.x*v1.x+v1.y*v1.y+v1.z*v1.z+v1.w*v1.w;
            #pragma unroll
            for (int o = 32; o; o >>= 1){ s += __shfl_xor(s,o); sq += __shfl_xor(sq,o); }
            float m = s*(1.f/D), var = sq*(1.f/D) - m*m, rstd = rsqrtf(var + 1e-5f);
            bf16x8 ov;
            ov[0] = (bf16)((v0.x-m)*rstd*lg0.x + lb0.x);
            ov[1] = (bf16)((v0.y-m)*rstd*lg0.y + lb0.y);
            ov[2] = (bf16)((v0.z-m)*rstd*lg0.z + lb0.z);
            ov[3] = (bf16)((v0.w-m)*rstd*lg0.w + lb0.w);
            ov[4] = (bf16)((v1.x-m)*rstd*lg1.x + lb1.x);
            ov[5] = (bf16)((v1.y-m)*rstd*lg1.y + lb1.y);
            ov[6] = (bf16)((v1.z-m)*rstd*lg1.z + lb1.z);
            ov[7] = (bf16)((v1.w-m)*rstd*lg1.w + lb1.w);
            *(bf16x8*)&Abuf[r*AS + lane*8] = ov;
        }
    }
    __syncthreads();

    // ---- GEMM1: q = LN(x) @ Wq
    f32x4 acc[4][4];
    #pragma unroll
    for (int mt = 0; mt < 4; ++mt)
        #pragma unroll
        for (int nt = 0; nt < 4; ++nt) acc[mt][nt] = (f32x4){0.f,0.f,0.f,0.f};
    gemm_body(WqS + fragoff, Abuf, l15, grp, bpre, acc);

    // ---- softmax over this wave's head (in-register)
    {
        float bqv[4];
        #pragma unroll
        for (int nt = 0; nt < 4; ++nt) bqv[nt] = bq[wb + nt*16 + l15];
        #pragma unroll
        for (int mt = 0; mt < 4; ++mt)
            #pragma unroll
            for (int r = 0; r < 4; ++r){
                float v0 = acc[mt][0][r] + bqv[0];
                float v1 = acc[mt][1][r] + bqv[1];
                float v2 = acc[mt][2][r] + bqv[2];
                float v3 = acc[mt][3][r] + bqv[3];
                float mx = fmaxf(fmaxf(v0,v1), fmaxf(v2,v3));
                #pragma unroll
                for (int o = 1; o < 16; o <<= 1) mx = fmaxf(mx, __shfl_xor(mx, o));
                float e0 = __expf(v0-mx), e1 = __expf(v1-mx), e2 = __expf(v2-mx), e3 = __expf(v3-mx);
                float sden = e0+e1+e2+e3;
                #pragma unroll
                for (int o = 1; o < 16; o <<= 1) sden += __shfl_xor(sden, o);
                float inv = 1.f/sden;
                acc[mt][0][r] = e0*inv; acc[mt][1][r] = e1*inv;
                acc[mt][2][r] = e2*inv; acc[mt][3][r] = e3*inv;
            }
    }
    __syncthreads();   // all waves done reading Abuf (A of GEMM1) before overwrite

    // q (bf16) -> Abuf [all 64 rows][own 64 cols]
    #pragma unroll
    for (int mt = 0; mt < 4; ++mt)
        #pragma unroll
        for (int nt = 0; nt < 4; ++nt)
            #pragma unroll
            for (int r = 0; r < 4; ++r)
                Abuf[(mt*16 + grp*4 + r)*AS + wb + nt*16 + l15] = (bf16)acc[mt][nt][r];
    __syncthreads();   // cross-lane q visibility (transposed lane mapping)

    // ---- phase D: y = q @ att[head w]  (B from L2, fragment-ordered = coalesced)
    #pragma unroll
    for (int mt = 0; mt < 4; ++mt)
        #pragma unroll
        for (int nt = 0; nt < 4; ++nt) acc[mt][nt] = (f32x4){0.f,0.f,0.f,0.f};
    {
        const bf16* ab = attF + (((size_t)b*H + w) << 12);
        bf16x8 bfr[2][4];
        #pragma unroll
        for (int ks = 0; ks < 2; ++ks)
            #pragma unroll
            for (int n4 = 0; n4 < 4; ++n4)
                bfr[ks][n4] = *(const bf16x8*)&ab[(n4*2 + ks)*512 + lane*8];
        #pragma unroll
        for (int ks = 0; ks < 2; ++ks){
            bf16x8 qa[4];
            #pragma unroll
            for (int mt = 0; mt < 4; ++mt)
                qa[mt] = *(const bf16x8*)&Abuf[(mt*16 + l15)*AS + wb + ks*32 + grp*8];
            #pragma unroll
            for (int n4 = 0; n4 < 4; ++n4)
                #pragma unroll
                for (int mt = 0; mt < 4; ++mt)
                    acc[mt][n4] = __builtin_amdgcn_mfma_f32_16x16x32_bf16(qa[mt], bfr[ks][n4], acc[mt][n4], 0, 0, 0);
        }
    }

    // issue GEMM2 slices 0,1 now: they land during LN(y)-stats + stylize
    pf2(oWS + fragoff, bpre);

    // ---- LN(y) stats: per-wave partials -> LDS -> combine
    #pragma unroll
    for (int mt = 0; mt < 4; ++mt)
        #pragma unroll
        for (int r = 0; r < 4; ++r){
            float s = 0.f, q2 = 0.f;
            #pragma unroll
            for (int nt = 0; nt < 4; ++nt){ float v = acc[mt][nt][r]; s += v; q2 += v*v; }
            #pragma unroll
            for (int o = 1; o < 16; o <<= 1){ s += __shfl_xor(s, o); q2 += __shfl_xor(q2, o); }
            if (l15 == 0){ st_s[mt*16 + grp*4 + r][w] = s; st_q[mt*16 + grp*4 + r][w] = q2; }
        }
    __syncthreads();

    // ---- stylize + silu -> Abuf bf16
    {
        float sgv[4], sbv[4], sscv[4], sshv[4];
        #pragma unroll
        for (int nt = 0; nt < 4; ++nt){
            int col = wb + nt*16 + l15;
            sgv[nt] = sg[col]; sbv[nt] = sb[col];
            sscv[nt] = ssb[b*1024 + col]; sshv[nt] = ssb[b*1024 + 512 + col];
        }
        #pragma unroll
        for (int mt = 0; mt < 4; ++mt)
            #pragma unroll
            for (int r = 0; r < 4; ++r){
                int row = mt*16 + grp*4 + r;
                float4 s0 = *(const float4*)&st_s[row][0];
                float4 s1 = *(const float4*)&st_s[row][4];
                float4 q0 = *(const float4*)&st_q[row][0];
                float4 q1 = *(const float4*)&st_q[row][4];
                float m = (s0.x+s0.y+s0.z+s0.w + s1.x+s1.y+s1.z+s1.w)*(1.f/D);
                float var = (q0.x+q0.y+q0.z+q0.w + q1.x+q1.y+q1.z+q1.w)*(1.f/D) - m*m;
                float rstd = rsqrtf(var + 1e-5f);
                #pragma unroll
                for (int nt = 0; nt < 4; ++nt){
                    float yn = (acc[mt][nt][r] - m)*rstd*sgv[nt] + sbv[nt];
                    float h2 = yn*(1.f + sscv[nt]) + sshv[nt];
                    Abuf[row*AS + wb + nt*16 + l15] = (bf16)(h2 * sigmoidf_(h2));
                }
            }
    }
    __syncthreads();   // h complete across all waves before GEMM2 reads full K

    // ---- GEMM2: out = silu(h) @ out_W + ob + x
    #pragma unroll
    for (int mt = 0; mt < 4; ++mt)
        #pragma unroll
        for (int nt = 0; nt < 4; ++nt) acc[mt][nt] = (f32x4){0.f,0.f,0.f,0.f};
    gemm_body(oWS + fragoff, Abuf, l15, grp, bpre, acc);

    {
        float obv[4];
        #pragma unroll
        for (int nt = 0; nt < 4; ++nt) obv[nt] = ob[wb + nt*16 + l15];
        #pragma unroll
        for (int mt = 0; mt < 4; ++mt)
            #pragma unroll
            for (int r = 0; r < 4; ++r){
                size_t base = (size_t)(g0 + mt*16 + grp*4 + r)*D + wb + l15;
                #pragma unroll
                for (int nt = 0; nt < 4; ++nt){
                    size_t idx = base + nt*16;
                    out[idx] = acc[mt][nt][r] + obv[nt] + x[idx];
                }
            }
    }
}

extern "C" void kernel_launch(void* const* d_in, const int* in_sizes, int n_in,
                              void* d_out, int out_size, void* d_ws, size_t ws_size,
                              hipStream_t stream){
    const float* x     = (const float*)d_in[0];
    const float* xf    = (const float*)d_in[1];
    const float* emb   = (const float*)d_in[2];
    const float* Wq    = (const float*)d_in[3];
    const float* bq    = (const float*)d_in[4];
    const float* Wk    = (const float*)d_in[5];
    const float* bk    = (const float*)d_in[6];
    const float* Wv    = (const float*)d_in[7];
    const float* bv    = (const float*)d_in[8];
    const float* ln_g  = (const float*)d_in[9];
    const float* ln_b  = (const float*)d_in[10];
    const float* tln_g = (const float*)d_in[11];
    const float* tln_b = (const float*)d_in[12];
    const float* emb_W = (const float*)d_in[13];
    const float* emb_b = (const float*)d_in[14];
    const float* sn_g  = (const float*)d_in[15];
    const float* sn_b  = (const float*)d_in[16];
    const float* out_W = (const float*)d_in[17];
    const float* out_b = (const float*)d_in[18];
    float* out = (float*)d_out;

    // workspace carve
    float* ssb  = (float*)d_ws;                          // B*1024 f32
    bf16*  kbuf = (bf16*)(ssb + B*1024);                 // B*NN*D bf16
    bf16*  vbuf = kbuf + (size_t)B*NN*D;                 // B*NN*D bf16
    bf16*  attF = vbuf + (size_t)B*NN*D;                 // B*H*DH*DH bf16
    bf16*  wqS  = attF + (size_t)B*H*DH*DH;              // D*D bf16 (staged layout)
    bf16*  owS  = wqS  + (size_t)D*D;                    // D*D bf16

    k_prep<<<dim3(448),    dim3(256), 0, stream>>>(Wq, out_W, wqS, owS,
                                                   emb, emb_W, emb_b, ssb,
                                                   xf, Wk, bk, Wv, bv, tln_g, tln_b, kbuf, vbuf);
    k_att <<<dim3(H, B),   dim3(256), 0, stream>>>(kbuf, vbuf, attF);
    k_main<<<dim3(B*T/MR), dim3(512), 0, stream>>>(x, wqS, bq, ln_g, ln_b, attF, ssb,
                                                   sn_g, sn_b, owS, out_b, out);
}

// Round 7
// 179.840 us; speedup vs baseline: 3.7205x; 1.0118x over previous
//
#include <hip/hip_runtime.h>
#include <math.h>
#include <stdint.h>

#define B 4
#define T 8192
#define D 512
#define NN 256
#define L 768
#define TE 2048
#define H 8
#define DH 64
#define MR 64
#define AS 520          // Abuf row stride (bf16 elems)
#define SLICE 16384     // elems per 32-K staged B slice (512 cols * 32 k)

typedef __bf16 bf16;
typedef bf16  bf16x8 __attribute__((ext_vector_type(8)));
typedef float f32x4  __attribute__((ext_vector_type(4)));

__device__ __forceinline__ float sigmoidf_(float x){ return 1.0f/(1.0f+__expf(-x)); }

// ======== fused prep ========
// [0,128): weight re-layout  W (f32 [k][n]) -> Wst bf16 [kk][col][k']  (kk = k/32)
// [128,192): ss = silu(emb) @ emb_W + emb_b (all 4 batches per block)
// [192,448): kv: LN(xf) + k/v projection; block = (16-row group) x (128-col quarter)
__global__ __launch_bounds__(256) void k_prep(
    const float* __restrict__ Wq, const float* __restrict__ oW,
    bf16* __restrict__ wqS, bf16* __restrict__ owS,
    const float* __restrict__ emb, const float* __restrict__ emb_W,
    const float* __restrict__ emb_b, float* __restrict__ ss,
    const float* __restrict__ xf, const float* __restrict__ Wk,
    const float* __restrict__ bk, const float* __restrict__ Wv,
    const float* __restrict__ bv, const float* __restrict__ tg,
    const float* __restrict__ tb, bf16* __restrict__ kbuf, bf16* __restrict__ vbuf){
    __shared__ __align__(16) char smem[49408];
    const int bid = blockIdx.x, t = threadIdx.x;
    if (bid < 128){
        const float* W = (bid < 64) ? Wq : oW;
        bf16* Wst = (bid < 64) ? wqS : owS;
        int lb = bid & 63;
        int k0 = (lb & 7)*64, n0 = (lb >> 3)*64;
        float (*tile)[65] = (float(*)[65])smem;
        int c = t & 63, r4 = t >> 6;
        #pragma unroll
        for (int p = 0; p < 16; ++p){ int r = p*4 + r4; tile[r][c] = W[(size_t)(k0+r)*D + n0 + c]; }
        __syncthreads();
        int oct = t >> 6, col = t & 63;
        #pragma unroll
        for (int half = 0; half < 2; ++half){
            int kk = (lb & 7)*2 + half;
            bf16x8 ov;
            #pragma unroll
            for (int j = 0; j < 8; ++j) ov[j] = (bf16)tile[half*32 + oct*8 + j][col];
            *(bf16x8*)&Wst[(size_t)kk*SLICE + (n0+col)*32 + oct*8] = ov;
        }
    } else if (bid < 192){
        // ss for all 4 batches; block owns 16 output cols (c*16..)
        float (*semb)[TE] = (float(*)[TE])smem;                 // 4*2048*4 = 32KB
        float (*red)[64]  = (float(*)[64])(smem + 4*TE*4);      // 16*64*4  = 4KB
        int c = bid - 128;
        for (int i = t; i < TE; i += 256)
            #pragma unroll
            for (int b = 0; b < B; ++b){ float e = emb[b*TE + i]; semb[b][i] = e * sigmoidf_(e); }
        __syncthreads();
        int o = t & 15, p = t >> 4;
        int j = c*16 + o;
        float acc[B] = {0.f,0.f,0.f,0.f};
        for (int i = 0; i < 128; ++i){
            int e = p*128 + i;
            float wv = emb_W[(size_t)e*1024 + j];
            #pragma unroll
            for (int b = 0; b < B; ++b) acc[b] += semb[b][e] * wv;
        }
        #pragma unroll
        for (int b = 0; b < B; ++b) red[p][b*16 + o] = acc[b];
        __syncthreads();
        if (t < 64){
            int b = t >> 4, o2 = t & 15;
            int j2 = c*16 + o2;
            float s = 0.f;
            #pragma unroll
            for (int pp = 0; pp < 16; ++pp) s += red[pp][b*16 + o2];
            ss[b*1024 + j2] = s + emb_b[j2];
        }
    } else {
        // kv: 16 rows, 128-col quarter (k for t<128, v for t>=128)
        float (*xfn)[L] = (float(*)[L])smem;                    // 16*768*4 = 48KB
        int lb = bid - 192;
        int g0 = (lb >> 2) * 16, jc = lb & 3;
        int wave = t >> 6, lane = t & 63;
        #pragma unroll
        for (int rr = 0; rr < 4; ++rr){
            int r = wave*4 + rr, g = g0 + r;
            float vals[12];
            float s = 0.f, sq = 0.f;
            #pragma unroll
            for (int i = 0; i < 12; ++i){ float v = xf[(size_t)g*L + lane*12 + i]; vals[i] = v; s += v; sq += v*v; }
            #pragma unroll
            for (int o = 32; o; o >>= 1){ s += __shfl_xor(s, o); sq += __shfl_xor(sq, o); }
            float m = s / L; float var = sq / L - m*m;
            float rstd = rsqrtf(var + 1e-5f);
            #pragma unroll
            for (int i = 0; i < 12; ++i){
                int l = lane*12 + i;
                xfn[r][l] = (vals[i]-m)*rstd*tg[l] + tb[l];
            }
        }
        __syncthreads();
        const float* Wm = (t < 128) ? Wk : Wv;
        int col = jc*128 + (t & 127);
        float acc[16];
        #pragma unroll
        for (int r = 0; r < 16; ++r) acc[r] = 0.f;
        for (int l = 0; l < L; l += 4){
            float4 xv[16];
            #pragma unroll
            for (int r = 0; r < 16; ++r) xv[r] = *(const float4*)&xfn[r][l];
            #pragma unroll
            for (int u = 0; u < 4; ++u){
                float wv = Wm[(size_t)(l+u)*D + col];
                #pragma unroll
                for (int r = 0; r < 16; ++r) acc[r] += ((const float*)&xv[r])[u] * wv;
            }
        }
        float bias = (t < 128) ? bk[col] : bv[col];
        bf16* dst = (t < 128) ? kbuf : vbuf;
        #pragma unroll
        for (int r = 0; r < 16; ++r){
            size_t g = (size_t)(g0 + r);
            dst[g*D + col] = (bf16)(acc[r] + bias);
        }
    }
}

// ======== k-softmax over N; attF = fragment-ordered per-head state (bf16) ========
__global__ void k_att(const bf16* __restrict__ kbuf, const bf16* __restrict__ vbuf,
                      bf16* __restrict__ attF){
    __shared__ float kh[NN*DH];
    __shared__ float vh[NN*DH];
    __shared__ float pm[4][DH], ps[4][DH];
    int t = threadIdx.x, h = blockIdx.x, b = blockIdx.y;
    for (int k = 0; k < NN*DH/256; ++k){
        int m = k*256 + t;
        int n = m >> 6, dl = m & 63;
        size_t src = (size_t)(b*NN + n)*D + h*DH + dl;
        kh[m] = (float)kbuf[src]; vh[m] = (float)vbuf[src];
    }
    __syncthreads();
    int d = t & 63, c = t >> 6;
    float mx = -1e30f;
    for (int n = c*64; n < c*64+64; ++n) mx = fmaxf(mx, kh[n*DH + d]);
    pm[c][d] = mx;
    __syncthreads();
    mx = fmaxf(fmaxf(pm[0][d], pm[1][d]), fmaxf(pm[2][d], pm[3][d]));
    float s = 0.f;
    for (int n = c*64; n < c*64+64; ++n){ float e = __expf(kh[n*DH + d] - mx); kh[n*DH + d] = e; s += e; }
    ps[c][d] = s;
    __syncthreads();
    float inv = 1.f/(ps[0][d] + ps[1][d] + ps[2][d] + ps[3][d]);
    for (int n = c*64; n < c*64+64; ++n) kh[n*DH + d] *= inv;
    __syncthreads();
    int l = t >> 2, dd0 = (t & 3)*16;
    float acc[16];
    #pragma unroll
    for (int i = 0; i < 16; ++i) acc[i] = 0.f;
    for (int n = 0; n < NN; ++n){
        float vv = vh[n*DH + l];
        #pragma unroll
        for (int i = 0; i < 16; ++i) acc[i] += kh[n*DH + dd0 + i] * vv;
    }
    size_t hbase = ((size_t)(b*H + h)) << 12;
    #pragma unroll
    for (int half = 0; half < 2; ++half){
        int d0 = dd0 + half*8;
        int f  = (l >> 4)*2 + (d0 >> 5);
        int ln = ((d0 >> 3) & 3)*16 + (l & 15);
        bf16x8 ov;
        #pragma unroll
        for (int j = 0; j < 8; ++j) ov[j] = (bf16)acc[half*8 + j];
        *(bf16x8*)&attF[hbase + f*512 + ln*8] = ov;
    }
}

// ======== rolled, register-double-buffered GEMM over K=512 ========
// 7 iterations x 2 slices + tail; B prefetched 2 slices ahead in VGPRs;
// A (LDS) reloaded per body. Compact code (I$) + static reg indexing.
__device__ __forceinline__ void gemm_body(const bf16* __restrict__ wfrag,
                                          const bf16* __restrict__ afrag,
                                          f32x4 (&acc)[4][4]){
    bf16x8 b0[4], b1[4];
    #pragma unroll
    for (int nt = 0; nt < 4; ++nt) b0[nt] = *(const bf16x8*)&wfrag[nt*512];
    #pragma unroll
    for (int nt = 0; nt < 4; ++nt) b1[nt] = *(const bf16x8*)&wfrag[SLICE + nt*512];
    const bf16* wp = wfrag + 2*(size_t)SLICE;
    const bf16* ap = afrag;
    for (int kk = 0; kk < 14; kk += 2){
        bf16x8 aa[4];
        #pragma unroll
        for (int mt = 0; mt < 4; ++mt) aa[mt] = *(const bf16x8*)&ap[mt*16*AS];
        #pragma unroll
        for (int nt = 0; nt < 4; ++nt)
            #pragma unroll
            for (int mt = 0; mt < 4; ++mt)
                acc[mt][nt] = __builtin_amdgcn_mfma_f32_16x16x32_bf16(aa[mt], b0[nt], acc[mt][nt], 0, 0, 0);
        #pragma unroll
        for (int nt = 0; nt < 4; ++nt) b0[nt] = *(const bf16x8*)&wp[nt*512];
        #pragma unroll
        for (int mt = 0; mt < 4; ++mt) aa[mt] = *(const bf16x8*)&ap[mt*16*AS + 32];
        #pragma unroll
        for (int nt = 0; nt < 4; ++nt)
            #pragma unroll
            for (int mt = 0; mt < 4; ++mt)
                acc[mt][nt] = __builtin_amdgcn_mfma_f32_16x16x32_bf16(aa[mt], b1[nt], acc[mt][nt], 0, 0, 0);
        #pragma unroll
        for (int nt = 0; nt < 4; ++nt) b1[nt] = *(const bf16x8*)&wp[SLICE + nt*512];
        wp += 2*(size_t)SLICE; ap += 64;
    }
    // tail: slices 14,15 already in b0,b1; ap at +448
    {
        bf16x8 aa[4];
        #pragma unroll
        for (int mt = 0; mt < 4; ++mt) aa[mt] = *(const bf16x8*)&ap[mt*16*AS];
        #pragma unroll
        for (int nt = 0; nt < 4; ++nt)
            #pragma unroll
            for (int mt = 0; mt < 4; ++mt)
                acc[mt][nt] = __builtin_amdgcn_mfma_f32_16x16x32_bf16(aa[mt], b0[nt], acc[mt][nt], 0, 0, 0);
        #pragma unroll
        for (int mt = 0; mt < 4; ++mt) aa[mt] = *(const bf16x8*)&ap[mt*16*AS + 32];
        #pragma unroll
        for (int nt = 0; nt < 4; ++nt)
            #pragma unroll
            for (int mt = 0; mt < 4; ++mt)
                acc[mt][nt] = __builtin_amdgcn_mfma_f32_16x16x32_bf16(aa[mt], b1[nt], acc[mt][nt], 0, 0, 0);
    }
}

// ======== main fused kernel: 64 rows/block, 8 waves (1 head each), 2 blocks/CU ========
__global__ __launch_bounds__(512, 4) void k_main(
    const float* __restrict__ x, const bf16* __restrict__ WqS, const float* __restrict__ bq,
    const float* __restrict__ lg, const float* __restrict__ lb,
    const bf16* __restrict__ attF, const float* __restrict__ ssb,
    const float* __restrict__ sg, const float* __restrict__ sb,
    const bf16* __restrict__ oWS, const float* __restrict__ ob,
    float* __restrict__ out){
    __shared__ __align__(16) bf16 Abuf[MR*AS];      // 66.6 KB: LN(x) -> q -> silu(h) -> f32 scratch
    __shared__ float st_s[MR][8];
    __shared__ float st_q[MR][8];
    const int t = threadIdx.x, w = t >> 6, lane = t & 63;
    const int l15 = lane & 15, grp = lane >> 4;
    const long g0 = (long)blockIdx.x * MR;
    const int b = (int)(g0 / T);
    const int wb = w * 64;
    const size_t fragoff = (size_t)w*2048 + (size_t)l15*32 + (size_t)grp*8;

    // ---- phase A: LN(x) -> Abuf bf16 (8 rows per wave, rolled)
    {
        float4 lg0 = *(const float4*)&lg[lane*8], lg1 = *(const float4*)&lg[lane*8+4];
        float4 lb0 = *(const float4*)&lb[lane*8], lb1 = *(const float4*)&lb[lane*8+4];
        #pragma unroll 2
        for (int rr = 0; rr < 8; ++rr){
            int r = w*8 + rr;
            const float* xp = &x[(size_t)(g0 + r)*D + lane*8];
            float4 v0 = *(const float4*)xp, v1 = *(const float4*)(xp+4);
            float s  = v0.x+v0.y+v0.z+v0.w + v1.x+v1.y+v1.z+v1.w;
            float sq = v0.x*v0.x+v0.y*v0.y+v0.z*v0.z+v0.w*v0.w
                     + v1.x*v1.x+v1.y*v1.y+v1.z*v1.z+v1.w*v1.w;
            #pragma unroll
            for (int o = 32; o; o >>= 1){ s += __shfl_xor(s,o); sq += __shfl_xor(sq,o); }
            float m = s*(1.f/D), var = sq*(1.f/D) - m*m, rstd = rsqrtf(var + 1e-5f);
            bf16x8 ov;
            ov[0] = (bf16)((v0.x-m)*rstd*lg0.x + lb0.x);
            ov[1] = (bf16)((v0.y-m)*rstd*lg0.y + lb0.y);
            ov[2] = (bf16)((v0.z-m)*rstd*lg0.z + lb0.z);
            ov[3] = (bf16)((v0.w-m)*rstd*lg0.w + lb0.w);
            ov[4] = (bf16)((v1.x-m)*rstd*lg1.x + lb1.x);
            ov[5] = (bf16)((v1.y-m)*rstd*lg1.y + lb1.y);
            ov[6] = (bf16)((v1.z-m)*rstd*lg1.z + lb1.z);
            ov[7] = (bf16)((v1.w-m)*rstd*lg1.w + lb1.w);
            *(bf16x8*)&Abuf[r*AS + lane*8] = ov;
        }
    }
    __syncthreads();

    // ---- GEMM1: q = LN(x) @ Wq
    f32x4 acc[4][4];
    #pragma unroll
    for (int mt = 0; mt < 4; ++mt)
        #pragma unroll
        for (int nt = 0; nt < 4; ++nt) acc[mt][nt] = (f32x4){0.f,0.f,0.f,0.f};
    gemm_body(WqS + fragoff, &Abuf[l15*AS + grp*8], acc);

    // ---- softmax over this wave's head (in-register)
    {
        float bqv[4];
        #pragma unroll
        for (int nt = 0; nt < 4; ++nt) bqv[nt] = bq[wb + nt*16 + l15];
        #pragma unroll
        for (int mt = 0; mt < 4; ++mt)
            #pragma unroll
            for (int r = 0; r < 4; ++r){
                float v0 = acc[mt][0][r] + bqv[0];
                float v1 = acc[mt][1][r] + bqv[1];
                float v2 = acc[mt][2][r] + bqv[2];
                float v3 = acc[mt][3][r] + bqv[3];
                float mx = fmaxf(fmaxf(v0,v1), fmaxf(v2,v3));
                #pragma unroll
                for (int o = 1; o < 16; o <<= 1) mx = fmaxf(mx, __shfl_xor(mx, o));
                float e0 = __expf(v0-mx), e1 = __expf(v1-mx), e2 = __expf(v2-mx), e3 = __expf(v3-mx);
                float sden = e0+e1+e2+e3;
                #pragma unroll
                for (int o = 1; o < 16; o <<= 1) sden += __shfl_xor(sden, o);
                float inv = 1.f/sden;
                acc[mt][0][r] = e0*inv; acc[mt][1][r] = e1*inv;
                acc[mt][2][r] = e2*inv; acc[mt][3][r] = e3*inv;
            }
    }
    __syncthreads();   // all waves done reading Abuf (A of GEMM1) before overwrite

    // q (bf16) -> Abuf [all 64 rows][own 64 cols]
    #pragma unroll
    for (int mt = 0; mt < 4; ++mt)
        #pragma unroll
        for (int nt = 0; nt < 4; ++nt)
            #pragma unroll
            for (int r = 0; r < 4; ++r)
                Abuf[(mt*16 + grp*4 + r)*AS + wb + nt*16 + l15] = (bf16)acc[mt][nt][r];
    __syncthreads();   // cross-lane q visibility (transposed lane mapping)

    // ---- phase D: y = q @ att[head w]  (B from L2, fragment-ordered = coalesced)
    #pragma unroll
    for (int mt = 0; mt < 4; ++mt)
        #pragma unroll
        for (int nt = 0; nt < 4; ++nt) acc[mt][nt] = (f32x4){0.f,0.f,0.f,0.f};
    {
        const bf16* ab = attF + (((size_t)b*H + w) << 12);
        bf16x8 bfr[2][4];
        #pragma unroll
        for (int ks = 0; ks < 2; ++ks)
            #pragma unroll
            for (int n4 = 0; n4 < 4; ++n4)
                bfr[ks][n4] = *(const bf16x8*)&ab[(n4*2 + ks)*512 + lane*8];
        #pragma unroll
        for (int ks = 0; ks < 2; ++ks){
            bf16x8 qa[4];
            #pragma unroll
            for (int mt = 0; mt < 4; ++mt)
                qa[mt] = *(const bf16x8*)&Abuf[(mt*16 + l15)*AS + wb + ks*32 + grp*8];
            #pragma unroll
            for (int n4 = 0; n4 < 4; ++n4)
                #pragma unroll
                for (int mt = 0; mt < 4; ++mt)
                    acc[mt][n4] = __builtin_amdgcn_mfma_f32_16x16x32_bf16(qa[mt], bfr[ks][n4], acc[mt][n4], 0, 0, 0);
        }
    }

    // ---- LN(y) stats: per-wave partials -> LDS -> combine
    #pragma unroll
    for (int mt = 0; mt < 4; ++mt)
        #pragma unroll
        for (int r = 0; r < 4; ++r){
            float s = 0.f, q2 = 0.f;
            #pragma unroll
            for (int nt = 0; nt < 4; ++nt){ float v = acc[mt][nt][r]; s += v; q2 += v*v; }
            #pragma unroll
            for (int o = 1; o < 16; o <<= 1){ s += __shfl_xor(s, o); q2 += __shfl_xor(q2, o); }
            if (l15 == 0){ st_s[mt*16 + grp*4 + r][w] = s; st_q[mt*16 + grp*4 + r][w] = q2; }
        }
    __syncthreads();

    // ---- stylize + silu -> Abuf bf16
    {
        float sgv[4], sbv[4], sscv[4], sshv[4];
        #pragma unroll
        for (int nt = 0; nt < 4; ++nt){
            int col = wb + nt*16 + l15;
            sgv[nt] = sg[col]; sbv[nt] = sb[col];
            sscv[nt] = ssb[b*1024 + col]; sshv[nt] = ssb[b*1024 + 512 + col];
        }
        #pragma unroll
        for (int mt = 0; mt < 4; ++mt)
            #pragma unroll
            for (int r = 0; r < 4; ++r){
                int row = mt*16 + grp*4 + r;
                float4 s0 = *(const float4*)&st_s[row][0];
                float4 s1 = *(const float4*)&st_s[row][4];
                float4 q0 = *(const float4*)&st_q[row][0];
                float4 q1 = *(const float4*)&st_q[row][4];
                float m = (s0.x+s0.y+s0.z+s0.w + s1.x+s1.y+s1.z+s1.w)*(1.f/D);
                float var = (q0.x+q0.y+q0.z+q0.w + q1.x+q1.y+q1.z+q1.w)*(1.f/D) - m*m;
                float rstd = rsqrtf(var + 1e-5f);
                #pragma unroll
                for (int nt = 0; nt < 4; ++nt){
                    float yn = (acc[mt][nt][r] - m)*rstd*sgv[nt] + sbv[nt];
                    float h2 = yn*(1.f + sscv[nt]) + sshv[nt];
                    Abuf[row*AS + wb + nt*16 + l15] = (bf16)(h2 * sigmoidf_(h2));
                }
            }
    }
    __syncthreads();   // h complete across all waves before GEMM2 reads full K

    // ---- GEMM2: out_pre = silu(h) @ out_W
    #pragma unroll
    for (int mt = 0; mt < 4; ++mt)
        #pragma unroll
        for (int nt = 0; nt < 4; ++nt) acc[mt][nt] = (f32x4){0.f,0.f,0.f,0.f};
    gemm_body(oWS + fragoff, &Abuf[l15*AS + grp*8], acc);

    // ---- epilogue: LDS-bounce transpose -> coalesced (acc + ob + x) stores
    float* scr = (float*)Abuf;              // 32 rows x stride 516 f32 (66048B <= 66560B)
    #pragma unroll
    for (int half = 0; half < 2; ++half){
        __syncthreads();    // half0: all GEMM2 LDS reads done; half1: prev flush reads done
        #pragma unroll
        for (int mt2 = 0; mt2 < 2; ++mt2){
            int mt = half*2 + mt2;
            #pragma unroll
            for (int nt = 0; nt < 4; ++nt)
                #pragma unroll
                for (int r = 0; r < 4; ++r)
                    scr[(mt2*16 + grp*4 + r)*516 + wb + nt*16 + l15] = acc[mt][nt][r];
        }
        __syncthreads();
        #pragma unroll 2
        for (int i = 0; i < 8; ++i){
            int c = i*512 + t;
            int row = c >> 7, col4 = (c & 127) << 2;
            float4 v  = *(const float4*)&scr[row*516 + col4];
            size_t gi = (size_t)(g0 + half*32 + row)*D + col4;
            float4 xb = *(const float4*)&x[gi];
            float4 o4 = *(const float4*)&ob[col4];
            float4 r4 = {v.x+o4.x+xb.x, v.y+o4.y+xb.y, v.z+o4.z+xb.z, v.w+o4.w+xb.w};
            *(float4*)&out[gi] = r4;
        }
    }
}

extern "C" void kernel_launch(void* const* d_in, const int* in_sizes, int n_in,
                              void* d_out, int out_size, void* d_ws, size_t ws_size,
                              hipStream_t stream){
    const float* x     = (const float*)d_in[0];
    const float* xf    = (const float*)d_in[1];
    const float* emb   = (const float*)d_in[2];
    const float* Wq    = (const float*)d_in[3];
    const float* bq    = (const float*)d_in[4];
    const float* Wk    = (const float*)d_in[5];
    const float* bk    = (const float*)d_in[6];
    const float* Wv    = (const float*)d_in[7];
    const float* bv    = (const float*)d_in[8];
    const float* ln_g  = (const float*)d_in[9];
    const float* ln_b  = (const float*)d_in[10];
    const float* tln_g = (const float*)d_in[11];
    const float* tln_b = (const float*)d_in[12];
    const float* emb_W = (const float*)d_in[13];
    const float* emb_b = (const float*)d_in[14];
    const float* sn_g  = (const float*)d_in[15];
    const float* sn_b  = (const float*)d_in[16];
    const float* out_W = (const float*)d_in[17];
    const float* out_b = (const float*)d_in[18];
    float* out = (float*)d_out;

    // workspace carve
    float* ssb  = (float*)d_ws;                          // B*1024 f32
    bf16*  kbuf = (bf16*)(ssb + B*1024);                 // B*NN*D bf16
    bf16*  vbuf = kbuf + (size_t)B*NN*D;                 // B*NN*D bf16
    bf16*  attF = vbuf + (size_t)B*NN*D;                 // B*H*DH*DH bf16
    bf16*  wqS  = attF + (size_t)B*H*DH*DH;              // D*D bf16 (staged layout)
    bf16*  owS  = wqS  + (size_t)D*D;                    // D*D bf16

    k_prep<<<dim3(448),    dim3(256), 0, stream>>>(Wq, out_W, wqS, owS,
                                                   emb, emb_W, emb_b, ssb,
                                                   xf, Wk, bk, Wv, bv, tln_g, tln_b, kbuf, vbuf);
    k_att <<<dim3(H, B),   dim3(256), 0, stream>>>(kbuf, vbuf, attF);
    k_main<<<dim3(B*T/MR), dim3(512), 0, stream>>>(x, wqS, bq, ln_g, ln_b, attF, ssb,
                                                   sn_g, sn_b, owS, out_b, out);
}